// Round 1
// baseline (7023.554 us; speedup 1.0000x reference)
//
#include <hip/hip_runtime.h>
#include <hip/hip_bf16.h>
#include <math.h>

// Problem constants (match reference)
#define H_    8
#define DK_   32
#define NT_   6
#define ET_   3
#define DIM_  256
#define LN_EPS 1e-5f

// ---- float <-> sortable uint encoding for atomicMax on floats ----
__device__ __forceinline__ unsigned enc_f(float f){
    unsigned u = __float_as_uint(f);
    return (u & 0x80000000u) ? ~u : (u | 0x80000000u);
}
__device__ __forceinline__ float dec_f(unsigned u){
    return (u & 0x80000000u) ? __uint_as_float(u & 0x7fffffffu) : __uint_as_float(~u);
}

// ---------------- type-sort kernels ----------------
__global__ void k_count(const int* __restrict__ ntyp, int n, int* __restrict__ counts){
    int i = blockIdx.x * blockDim.x + threadIdx.x;
    if (i < n) atomicAdd(&counts[ntyp[i]], 1);
}

__global__ void k_scan(const int* __restrict__ counts, int* __restrict__ offs,
                       int* __restrict__ cursor, int* __restrict__ meta){
    // single thread: 6 types, ~790 tiles
    int off = 0, ntl = 0;
    for (int t = 0; t < NT_; t++){
        offs[t] = off; cursor[t] = off;
        int c = counts[t];
        for (int s = 0; s < c; s += 64){
            meta[1 + 3*ntl]     = t;
            meta[1 + 3*ntl + 1] = off + s;
            meta[1 + 3*ntl + 2] = (c - s < 64) ? (c - s) : 64;
            ntl++;
        }
        off += c;
    }
    meta[0] = ntl;
}

__global__ void k_scatter(const int* __restrict__ ntyp, int n, int* __restrict__ cursor,
                          int* __restrict__ sorted){
    int i = blockIdx.x * blockDim.x + threadIdx.x;
    if (i < n){
        int t = ntyp[i];
        int pos = atomicAdd(&cursor[t], 1);
        sorted[pos] = i;
    }
}

// ---------------- projection: K,Q,V = x @ W[type] + b[type] ----------------
// one block = one 64-row tile (all rows same type), 256 threads, 4x4 per thread per 64-col pass
__global__ __launch_bounds__(256) void k_proj(
    const float* __restrict__ x, const int* __restrict__ sorted, const int* __restrict__ meta,
    const float* __restrict__ Wk, const float* __restrict__ bk,
    const float* __restrict__ Wq, const float* __restrict__ bq,
    const float* __restrict__ Wv, const float* __restrict__ bv,
    float* __restrict__ K, float* __restrict__ Q, float* __restrict__ V)
{
    const int ntl = meta[0];
    const int tile = blockIdx.x;
    if (tile >= ntl) return;
    const int t     = meta[1 + 3*tile];
    const int start = meta[1 + 3*tile + 1];
    const int rows  = meta[1 + 3*tile + 2];

    __shared__ __align__(16) float xs[64][DIM_];
    __shared__ int ids[64];
    const int tid = threadIdx.x;
    if (tid < 64) ids[tid] = (tid < rows) ? sorted[start + tid] : 0;
    __syncthreads();

    for (int idx = tid; idx < rows * 64; idx += 256){
        int r = idx >> 6, c4 = idx & 63;
        float4 v4 = *reinterpret_cast<const float4*>(x + (size_t)ids[r] * DIM_ + c4 * 4);
        *reinterpret_cast<float4*>(&xs[r][c4 * 4]) = v4;
    }
    __syncthreads();

    const int tr4 = (tid >> 4) * 4;  // row group base (0..60)
    const int tc  = tid & 15;        // col group within 64-col pass

    const float* Ws[3] = {Wk + (size_t)t * DIM_ * DIM_, Wq + (size_t)t * DIM_ * DIM_, Wv + (size_t)t * DIM_ * DIM_};
    const float* Bs[3] = {bk + t * DIM_, bq + t * DIM_, bv + t * DIM_};
    float* Os[3] = {K, Q, V};

    for (int m = 0; m < 3; m++){
        const float* __restrict__ W = Ws[m];
        const float* __restrict__ B = Bs[m];
        float* __restrict__ O = Os[m];
        for (int cp = 0; cp < 4; cp++){
            const int col0 = cp * 64 + tc * 4;
            float acc[4][4];
            #pragma unroll
            for (int j = 0; j < 4; j++)
                #pragma unroll
                for (int c = 0; c < 4; c++) acc[j][c] = B[col0 + c];

            #pragma unroll 4
            for (int i = 0; i < DIM_; i++){
                float4 w4 = *reinterpret_cast<const float4*>(W + (size_t)i * DIM_ + col0);
                float wv0 = w4.x, wv1 = w4.y, wv2 = w4.z, wv3 = w4.w;
                #pragma unroll
                for (int j = 0; j < 4; j++){
                    float xv = xs[tr4 + j][i];
                    acc[j][0] = fmaf(xv, wv0, acc[j][0]);
                    acc[j][1] = fmaf(xv, wv1, acc[j][1]);
                    acc[j][2] = fmaf(xv, wv2, acc[j][2]);
                    acc[j][3] = fmaf(xv, wv3, acc[j][3]);
                }
            }
            #pragma unroll
            for (int j = 0; j < 4; j++){
                int r = tr4 + j;
                if (r < rows){
                    float4 o4 = make_float4(acc[j][0], acc[j][1], acc[j][2], acc[j][3]);
                    *reinterpret_cast<float4*>(O + (size_t)ids[r] * DIM_ + col0) = o4;
                }
            }
        }
    }
}

// ---------------- scores + per-(type,head) max ----------------
__global__ __launch_bounds__(256) void k_score(
    const float* __restrict__ K, const float* __restrict__ Q,
    const int* __restrict__ ei, const int* __restrict__ etyp,
    const float* __restrict__ Wa, const float* __restrict__ pri,
    float* __restrict__ scores, unsigned* __restrict__ gmax, int E_)
{
    __shared__ __align__(16) float wa[ET_ * DK_ * DK_];  // 12 KB, row-major [t][d][k]
    __shared__ unsigned smax[ET_ * H_];
    const int tid = threadIdx.x;
    for (int i = tid; i < ET_ * DK_ * DK_; i += 256) wa[i] = Wa[i];
    if (tid < ET_ * H_) smax[tid] = 0u;
    __syncthreads();

    const int idx = blockIdx.x * 256 + tid;
    const int EH = E_ * H_;
    if (idx < EH){
        const int e = idx >> 3, h = idx & 7;
        const int s = ei[e], tg = ei[E_ + e], t = etyp[e];

        float q[DK_], kk[DK_];
        #pragma unroll
        for (int k4 = 0; k4 < DK_ / 4; k4++){
            float4 v = *reinterpret_cast<const float4*>(Q + (size_t)tg * DIM_ + h * DK_ + k4 * 4);
            q[k4*4] = v.x; q[k4*4+1] = v.y; q[k4*4+2] = v.z; q[k4*4+3] = v.w;
        }
        #pragma unroll
        for (int k4 = 0; k4 < DK_ / 4; k4++){
            float4 v = *reinterpret_cast<const float4*>(K + (size_t)s * DIM_ + h * DK_ + k4 * 4);
            kk[k4*4] = v.x; kk[k4*4+1] = v.y; kk[k4*4+2] = v.z; kk[k4*4+3] = v.w;
        }

        const float* __restrict__ wat = &wa[t * DK_ * DK_];
        float acc = 0.f;
        #pragma unroll
        for (int d = 0; d < DK_; d++){
            float qh = 0.f;
            #pragma unroll
            for (int k4 = 0; k4 < 8; k4++){
                float4 w4 = *reinterpret_cast<const float4*>(&wat[d * DK_ + k4 * 4]);
                qh = fmaf(w4.x, q[k4*4],   qh);
                qh = fmaf(w4.y, q[k4*4+1], qh);
                qh = fmaf(w4.z, q[k4*4+2], qh);
                qh = fmaf(w4.w, q[k4*4+3], qh);
            }
            acc = fmaf(kk[d], qh, acc);
        }
        float score = acc * 0.17677669529663687f * pri[t * H_ + h];  // 1/sqrt(32)
        scores[idx] = score;
        atomicMax(&smax[t * H_ + h], enc_f(score));
    }
    __syncthreads();
    if (tid < ET_ * H_) atomicMax(&gmax[tid], smax[tid]);
}

// ---------------- exp + per-(type,head) sum ----------------
__global__ __launch_bounds__(256) void k_sum(
    const int* __restrict__ etyp, const unsigned* __restrict__ gmax,
    float* __restrict__ scores, float* __restrict__ gsum, int E_)
{
    __shared__ float ssum[ET_ * H_];
    const int tid = threadIdx.x;
    if (tid < ET_ * H_) ssum[tid] = 0.f;
    __syncthreads();
    const int idx = blockIdx.x * 256 + tid;
    if (idx < E_ * H_){
        const int e = idx >> 3, h = idx & 7;
        const int bin = etyp[e] * H_ + h;
        float m = dec_f(gmax[bin]);
        float v = __expf(scores[idx] - m);
        scores[idx] = v;
        atomicAdd(&ssum[bin], v);
    }
    __syncthreads();
    if (tid < ET_ * H_){
        float s = ssum[tid];
        if (s != 0.f) atomicAdd(&gsum[tid], s);
    }
}

// ---------------- weighted message aggregation (atomic segment-sum) ----------------
__global__ __launch_bounds__(256) void k_agg(
    const float* __restrict__ V, const int* __restrict__ ei, const int* __restrict__ etyp,
    const float* __restrict__ Wm, const float* __restrict__ scores,
    const float* __restrict__ gsum, float* __restrict__ out, int E_)
{
    // stage Wm TRANSPOSED: wmT[t][k][d] = Wm[t][d][k] so inner dot is contiguous
    __shared__ __align__(16) float wmT[ET_ * DK_ * DK_];
    const int tid = threadIdx.x;
    for (int i = tid; i < ET_ * DK_ * DK_; i += 256){
        int t = i >> 10, r = (i >> 5) & 31, c = i & 31;   // r=k, c=d
        wmT[i] = Wm[t * 1024 + c * 32 + r];
    }
    __syncthreads();

    const int idx = blockIdx.x * 256 + tid;
    if (idx >= E_ * H_) return;
    const int e = idx >> 3, h = idx & 7;
    const int s = ei[e], tg = ei[E_ + e], t = etyp[e];
    const float w = scores[idx] / gsum[t * H_ + h];

    float v[DK_];
    #pragma unroll
    for (int k4 = 0; k4 < DK_ / 4; k4++){
        float4 x4 = *reinterpret_cast<const float4*>(V + (size_t)s * DIM_ + h * DK_ + k4 * 4);
        v[k4*4] = x4.x; v[k4*4+1] = x4.y; v[k4*4+2] = x4.z; v[k4*4+3] = x4.w;
    }
    const float* __restrict__ wt = &wmT[t * DK_ * DK_];
    float* __restrict__ o = out + (size_t)tg * DIM_ + h * DK_;
    #pragma unroll 2
    for (int k = 0; k < DK_; k++){
        float vh = 0.f;
        #pragma unroll
        for (int d4 = 0; d4 < 8; d4++){
            float4 w4 = *reinterpret_cast<const float4*>(&wt[k * DK_ + d4 * 4]);
            vh = fmaf(w4.x, v[d4*4],   vh);
            vh = fmaf(w4.y, v[d4*4+1], vh);
            vh = fmaf(w4.z, v[d4*4+2], vh);
            vh = fmaf(w4.w, v[d4*4+3], vh);
        }
        atomicAdd(&o[k], w * vh);
    }
}

// ---------------- skip + LayerNorm ----------------
__global__ __launch_bounds__(256) void k_ln(
    const float* __restrict__ x, const float* __restrict__ g, const float* __restrict__ b,
    float* __restrict__ out, int n)
{
    const int node = blockIdx.x;
    const int tid = threadIdx.x;
    float v = out[(size_t)node * DIM_ + tid] + x[(size_t)node * DIM_ + tid];

    float s = v, ss = v * v;
    #pragma unroll
    for (int off = 32; off > 0; off >>= 1){
        s  += __shfl_down(s, off, 64);
        ss += __shfl_down(ss, off, 64);
    }
    __shared__ float red[8];
    const int wv = tid >> 6, ln = tid & 63;
    if (ln == 0){ red[wv] = s; red[4 + wv] = ss; }
    __syncthreads();
    if (tid == 0){
        float S  = red[0] + red[1] + red[2] + red[3];
        float SS = red[4] + red[5] + red[6] + red[7];
        float mu = S / DIM_;
        red[0] = mu;
        red[1] = SS / DIM_ - mu * mu;
    }
    __syncthreads();
    const float mu = red[0], var = red[1];
    out[(size_t)node * DIM_ + tid] = (v - mu) * rsqrtf(var + LN_EPS) * g[tid] + b[tid];
}

extern "C" void kernel_launch(void* const* d_in, const int* in_sizes, int n_in,
                              void* d_out, int out_size, void* d_ws, size_t ws_size,
                              hipStream_t stream)
{
    const float* x   = (const float*)d_in[0];
    const int*  ei   = (const int*)d_in[1];
    const int*  ntyp = (const int*)d_in[3];
    const int*  etyp = (const int*)d_in[4];
    const float* Wk  = (const float*)d_in[5];
    const float* bk  = (const float*)d_in[6];
    const float* Wq  = (const float*)d_in[7];
    const float* bq  = (const float*)d_in[8];
    const float* Wv  = (const float*)d_in[9];
    const float* bv  = (const float*)d_in[10];
    const float* pri = (const float*)d_in[11];
    const float* Wa  = (const float*)d_in[12];
    const float* Wm  = (const float*)d_in[13];
    const float* lg  = (const float*)d_in[14];
    const float* lb  = (const float*)d_in[15];

    const int n  = in_sizes[0] / DIM_;
    const int E_ = in_sizes[4];
    float* out = (float*)d_out;

    // workspace layout (all f32 unless noted): K,Q,V [n*256], scores [E*8], then ints
    float* fws = (float*)d_ws;
    const size_t NF = (size_t)n * DIM_;
    float* Kb = fws;
    float* Qb = Kb + NF;
    float* Vb = Qb + NF;
    float* SC = Vb + NF;                       // E_*H_
    int* iws    = (int*)(SC + (size_t)E_ * H_);
    int* sorted = iws;                         // n
    int* counts = sorted + n;                  // 8
    int* offs   = counts + 8;                  // 8
    int* cursor = offs + 8;                    // 8
    int* meta   = cursor + 8;                  // 1 + 3*maxtiles
    const int maxtiles = (n + 63) / 64 + NT_;
    unsigned* gmax = (unsigned*)(meta + 1 + 3 * maxtiles);
    float*    gsum = (float*)(gmax + ET_ * H_);

    hipMemsetAsync(d_out, 0, NF * sizeof(float), stream);                 // agg accumulator
    hipMemsetAsync(counts, 0, 8 * sizeof(int), stream);
    hipMemsetAsync(gmax, 0, ET_ * H_ * sizeof(unsigned), stream);         // encoded -inf
    hipMemsetAsync(gsum, 0, ET_ * H_ * sizeof(float), stream);

    k_count  <<<(n + 255) / 256, 256, 0, stream>>>(ntyp, n, counts);
    k_scan   <<<1, 1, 0, stream>>>(counts, offs, cursor, meta);
    k_scatter<<<(n + 255) / 256, 256, 0, stream>>>(ntyp, n, cursor, sorted);
    k_proj   <<<maxtiles, 256, 0, stream>>>(x, sorted, meta, Wk, bk, Wq, bq, Wv, bv, Kb, Qb, Vb);

    const int EH = E_ * H_;
    k_score<<<(EH + 255) / 256, 256, 0, stream>>>(Kb, Qb, ei, etyp, Wa, pri, SC, gmax, E_);
    k_sum  <<<(EH + 255) / 256, 256, 0, stream>>>(etyp, gmax, SC, gsum, E_);
    k_agg  <<<(EH + 255) / 256, 256, 0, stream>>>(Vb, ei, etyp, Wm, SC, gsum, out, E_);
    k_ln   <<<n, 256, 0, stream>>>(x, lg, lb, out, n);
}

// Round 2
// 2186.843 us; speedup vs baseline: 3.2117x; 3.2117x over previous
//
#include <hip/hip_runtime.h>
#include <hip/hip_bf16.h>
#include <math.h>

// Problem constants (match reference)
#define H_    8
#define DK_   32
#define NT_   6
#define ET_   3
#define DIM_  256
#define LN_EPS 1e-5f
#define WM_STRIDE 1048   // per-type LDS stride: 1048 % 32 = 24 -> types land on banks 0/24/16

// ---- float <-> sortable uint encoding for atomicMax on floats ----
__device__ __forceinline__ unsigned enc_f(float f){
    unsigned u = __float_as_uint(f);
    return (u & 0x80000000u) ? ~u : (u | 0x80000000u);
}
__device__ __forceinline__ float dec_f(unsigned u){
    return (u & 0x80000000u) ? __uint_as_float(u & 0x7fffffffu) : __uint_as_float(~u);
}

// ---------------- node type-sort kernels ----------------
__global__ void k_count(const int* __restrict__ ntyp, int n, int* __restrict__ counts){
    int i = blockIdx.x * blockDim.x + threadIdx.x;
    if (i < n) atomicAdd(&counts[ntyp[i]], 1);
}

__global__ void k_scan(const int* __restrict__ counts, int* __restrict__ offs,
                       int* __restrict__ cursor, int* __restrict__ meta){
    int off = 0, ntl = 0;
    for (int t = 0; t < NT_; t++){
        offs[t] = off; cursor[t] = off;
        int c = counts[t];
        for (int s = 0; s < c; s += 64){
            meta[1 + 3*ntl]     = t;
            meta[1 + 3*ntl + 1] = off + s;
            meta[1 + 3*ntl + 2] = (c - s < 64) ? (c - s) : 64;
            ntl++;
        }
        off += c;
    }
    meta[0] = ntl;
}

__global__ void k_scatter(const int* __restrict__ ntyp, int n, int* __restrict__ cursor,
                          int* __restrict__ sorted){
    int i = blockIdx.x * blockDim.x + threadIdx.x;
    if (i < n){
        int t = ntyp[i];
        int pos = atomicAdd(&cursor[t], 1);
        sorted[pos] = i;
    }
}

// ---------------- projection: K,Q,V = x @ W[type] + b[type] ----------------
__global__ __launch_bounds__(256) void k_proj(
    const float* __restrict__ x, const int* __restrict__ sorted, const int* __restrict__ meta,
    const float* __restrict__ Wk, const float* __restrict__ bk,
    const float* __restrict__ Wq, const float* __restrict__ bq,
    const float* __restrict__ Wv, const float* __restrict__ bv,
    float* __restrict__ K, float* __restrict__ Q, float* __restrict__ V)
{
    const int ntl = meta[0];
    const int tile = blockIdx.x;
    if (tile >= ntl) return;
    const int t     = meta[1 + 3*tile];
    const int start = meta[1 + 3*tile + 1];
    const int rows  = meta[1 + 3*tile + 2];

    __shared__ __align__(16) float xs[64][DIM_];
    __shared__ int ids[64];
    const int tid = threadIdx.x;
    if (tid < 64) ids[tid] = (tid < rows) ? sorted[start + tid] : 0;
    __syncthreads();

    for (int idx = tid; idx < rows * 64; idx += 256){
        int r = idx >> 6, c4 = idx & 63;
        float4 v4 = *reinterpret_cast<const float4*>(x + (size_t)ids[r] * DIM_ + c4 * 4);
        *reinterpret_cast<float4*>(&xs[r][c4 * 4]) = v4;
    }
    __syncthreads();

    const int tr4 = (tid >> 4) * 4;
    const int tc  = tid & 15;

    const float* Ws[3] = {Wk + (size_t)t * DIM_ * DIM_, Wq + (size_t)t * DIM_ * DIM_, Wv + (size_t)t * DIM_ * DIM_};
    const float* Bs[3] = {bk + t * DIM_, bq + t * DIM_, bv + t * DIM_};
    float* Os[3] = {K, Q, V};

    for (int m = 0; m < 3; m++){
        const float* __restrict__ W = Ws[m];
        const float* __restrict__ B = Bs[m];
        float* __restrict__ O = Os[m];
        for (int cp = 0; cp < 4; cp++){
            const int col0 = cp * 64 + tc * 4;
            float acc[4][4];
            #pragma unroll
            for (int j = 0; j < 4; j++)
                #pragma unroll
                for (int c = 0; c < 4; c++) acc[j][c] = B[col0 + c];

            #pragma unroll 4
            for (int i = 0; i < DIM_; i++){
                float4 w4 = *reinterpret_cast<const float4*>(W + (size_t)i * DIM_ + col0);
                float wv0 = w4.x, wv1 = w4.y, wv2 = w4.z, wv3 = w4.w;
                #pragma unroll
                for (int j = 0; j < 4; j++){
                    float xv = xs[tr4 + j][i];
                    acc[j][0] = fmaf(xv, wv0, acc[j][0]);
                    acc[j][1] = fmaf(xv, wv1, acc[j][1]);
                    acc[j][2] = fmaf(xv, wv2, acc[j][2]);
                    acc[j][3] = fmaf(xv, wv3, acc[j][3]);
                }
            }
            #pragma unroll
            for (int j = 0; j < 4; j++){
                int r = tr4 + j;
                if (r < rows){
                    float4 o4 = make_float4(acc[j][0], acc[j][1], acc[j][2], acc[j][3]);
                    *reinterpret_cast<float4*>(O + (size_t)ids[r] * DIM_ + col0) = o4;
                }
            }
        }
    }
}

// ---------------- edge CSR-by-target build ----------------
__global__ void k_ecount(const int* __restrict__ ei, int E_, int* __restrict__ ecnt){
    int e = blockIdx.x * blockDim.x + threadIdx.x;
    if (e < E_) atomicAdd(&ecnt[ei[E_ + e]], 1);
}

__global__ __launch_bounds__(256) void k_scan1(const int* __restrict__ ecnt, int n,
                                               int* __restrict__ excl, int* __restrict__ bsum){
    __shared__ int sh[256];
    const int tid = threadIdx.x;
    const int gi = blockIdx.x * 256 + tid;
    int v = (gi < n) ? ecnt[gi] : 0;
    sh[tid] = v;
    __syncthreads();
    for (int off = 1; off < 256; off <<= 1){
        int t = (tid >= off) ? sh[tid - off] : 0;
        __syncthreads();
        sh[tid] += t;
        __syncthreads();
    }
    if (gi < n) excl[gi] = sh[tid] - v;   // exclusive within block
    if (tid == 255) bsum[blockIdx.x] = sh[255];
}

__global__ void k_scan2(int* __restrict__ bsum, int nb){
    // single thread exclusive scan of block sums (nb ~ 196)
    int run = 0;
    for (int b = 0; b < nb; b++){ int c = bsum[b]; bsum[b] = run; run += c; }
}

__global__ __launch_bounds__(256) void k_scan3(int n, int E_, const int* __restrict__ bsum,
                                               int* __restrict__ eoff, int* __restrict__ cursor){
    const int gi = blockIdx.x * 256 + threadIdx.x;
    if (gi < n){
        int v = eoff[gi] + bsum[blockIdx.x];
        eoff[gi] = v;
        cursor[gi] = v;
    }
    if (gi == 0) eoff[n] = E_;
}

__global__ void k_escatter(const int* __restrict__ ei, const int* __restrict__ etyp, int E_,
                           int* __restrict__ cursor, int* __restrict__ payload,
                           int* __restrict__ eidx){
    int e = blockIdx.x * blockDim.x + threadIdx.x;
    if (e < E_){
        int tg = ei[E_ + e];
        int pos = atomicAdd(&cursor[tg], 1);
        payload[pos] = ei[e] | (etyp[e] << 28);
        eidx[pos] = e;
    }
}

// ---------------- scores + per-(type,head) max ----------------
__global__ __launch_bounds__(256) void k_score(
    const float* __restrict__ K, const float* __restrict__ Q,
    const int* __restrict__ ei, const int* __restrict__ etyp,
    const float* __restrict__ Wa, const float* __restrict__ pri,
    float* __restrict__ scores, unsigned* __restrict__ gmax, int E_)
{
    __shared__ __align__(16) float wa[ET_ * DK_ * DK_];
    __shared__ unsigned smax[ET_ * H_];
    const int tid = threadIdx.x;
    for (int i = tid; i < ET_ * DK_ * DK_; i += 256) wa[i] = Wa[i];
    if (tid < ET_ * H_) smax[tid] = 0u;
    __syncthreads();

    const int idx = blockIdx.x * 256 + tid;
    const int EH = E_ * H_;
    if (idx < EH){
        const int e = idx >> 3, h = idx & 7;
        const int s = ei[e], tg = ei[E_ + e], t = etyp[e];

        float q[DK_], kk[DK_];
        #pragma unroll
        for (int k4 = 0; k4 < DK_ / 4; k4++){
            float4 v = *reinterpret_cast<const float4*>(Q + (size_t)tg * DIM_ + h * DK_ + k4 * 4);
            q[k4*4] = v.x; q[k4*4+1] = v.y; q[k4*4+2] = v.z; q[k4*4+3] = v.w;
        }
        #pragma unroll
        for (int k4 = 0; k4 < DK_ / 4; k4++){
            float4 v = *reinterpret_cast<const float4*>(K + (size_t)s * DIM_ + h * DK_ + k4 * 4);
            kk[k4*4] = v.x; kk[k4*4+1] = v.y; kk[k4*4+2] = v.z; kk[k4*4+3] = v.w;
        }

        const float* __restrict__ wat = &wa[t * DK_ * DK_];
        float acc = 0.f;
        #pragma unroll
        for (int d = 0; d < DK_; d++){
            float qh = 0.f;
            #pragma unroll
            for (int k4 = 0; k4 < 8; k4++){
                float4 w4 = *reinterpret_cast<const float4*>(&wat[d * DK_ + k4 * 4]);
                qh = fmaf(w4.x, q[k4*4],   qh);
                qh = fmaf(w4.y, q[k4*4+1], qh);
                qh = fmaf(w4.z, q[k4*4+2], qh);
                qh = fmaf(w4.w, q[k4*4+3], qh);
            }
            acc = fmaf(kk[d], qh, acc);
        }
        float score = acc * 0.17677669529663687f * pri[t * H_ + h];
        scores[idx] = score;
        atomicMax(&smax[t * H_ + h], enc_f(score));
    }
    __syncthreads();
    if (tid < ET_ * H_) atomicMax(&gmax[tid], smax[tid]);
}

// ---------------- exp + per-(type,head) sum; re-emit scores in CSR order ----------------
__global__ __launch_bounds__(256) void k_sum(
    const int* __restrict__ eidx, const int* __restrict__ payload,
    const unsigned* __restrict__ gmax, const float* __restrict__ scores,
    float* __restrict__ sc_csr, float* __restrict__ gsum, int E_)
{
    __shared__ float ssum[ET_ * H_];
    const int tid = threadIdx.x;
    if (tid < ET_ * H_) ssum[tid] = 0.f;
    __syncthreads();
    const int idx = blockIdx.x * 256 + tid;
    if (idx < E_ * H_){
        const int pos = idx >> 3, h = idx & 7;
        const int e = eidx[pos];
        const int t = payload[pos] >> 28;
        const int bin = t * H_ + h;
        float m = dec_f(gmax[bin]);
        float v = __expf(scores[e * 8 + h] - m);
        sc_csr[idx] = v;
        atomicAdd(&ssum[bin], v);
    }
    __syncthreads();
    if (tid < ET_ * H_ && ssum[tid] != 0.f) atomicAdd(&gsum[tid], ssum[tid]);
}

// ---------------- gather aggregation + skip + LayerNorm (no atomics) ----------------
__global__ __launch_bounds__(256) void k_aggln(
    const float* __restrict__ V, const float* __restrict__ x,
    const int* __restrict__ eoff, const int* __restrict__ payload,
    const float* __restrict__ sc_csr, const float* __restrict__ gsum,
    const float* __restrict__ Wm, const float* __restrict__ g, const float* __restrict__ b,
    float* __restrict__ out, int n)
{
    __shared__ __align__(16) float wm[ET_ * WM_STRIDE];   // wm[t][k][d] = Wm[t][d][k]
    const int tid = threadIdx.x;
    for (int i = tid; i < ET_ * DK_ * DK_; i += 256){
        int t = i >> 10, r = (i >> 5) & 31, c = i & 31;   // r=k, c=d
        wm[t * WM_STRIDE + r * 32 + c] = Wm[t * 1024 + c * 32 + r];
    }
    __syncthreads();

    const int idx = blockIdx.x * 256 + tid;
    if (idx >= n * H_) return;
    const int tg = idx >> 3, h = idx & 7;

    float rw[ET_];
    #pragma unroll
    for (int t = 0; t < ET_; t++){
        float s = gsum[t * H_ + h];
        rw[t] = (s > 0.f) ? 1.f / s : 0.f;
    }

    float acc[DK_];
    #pragma unroll
    for (int k = 0; k < DK_; k++) acc[k] = 0.f;

    const int p1 = eoff[tg + 1];
    for (int pos = eoff[tg]; pos < p1; ++pos){
        const int pl = payload[pos];
        const int s = pl & 0x0FFFFFFF, t = pl >> 28;
        const float w = sc_csr[pos * 8 + h] * rw[t];

        float v[DK_];
        #pragma unroll
        for (int k4 = 0; k4 < 8; k4++){
            float4 v4 = *reinterpret_cast<const float4*>(V + (size_t)s * DIM_ + h * DK_ + k4 * 4);
            v[4*k4] = v4.x; v[4*k4+1] = v4.y; v[4*k4+2] = v4.z; v[4*k4+3] = v4.w;
        }
        const float* __restrict__ wt = &wm[t * WM_STRIDE];
        #pragma unroll 4
        for (int k = 0; k < DK_; k++){
            float vh = 0.f;
            const float4* __restrict__ w4p = reinterpret_cast<const float4*>(wt + k * 32);
            #pragma unroll
            for (int d4 = 0; d4 < 8; d4++){
                float4 w4 = w4p[d4];
                vh = fmaf(w4.x, v[4*d4],   vh);
                vh = fmaf(w4.y, v[4*d4+1], vh);
                vh = fmaf(w4.z, v[4*d4+2], vh);
                vh = fmaf(w4.w, v[4*d4+3], vh);
            }
            acc[k] = fmaf(w, vh, acc[k]);
        }
    }

    // skip connection
    #pragma unroll
    for (int k4 = 0; k4 < 8; k4++){
        float4 x4 = *reinterpret_cast<const float4*>(x + (size_t)tg * DIM_ + h * DK_ + k4 * 4);
        acc[4*k4] += x4.x; acc[4*k4+1] += x4.y; acc[4*k4+2] += x4.z; acc[4*k4+3] += x4.w;
    }

    // LayerNorm across the 8 head-lanes of this target (consecutive, 8-aligned)
    float s1 = 0.f, s2 = 0.f;
    #pragma unroll
    for (int k = 0; k < DK_; k++){ s1 += acc[k]; s2 = fmaf(acc[k], acc[k], s2); }
    #pragma unroll
    for (int m = 1; m <= 4; m <<= 1){
        s1 += __shfl_xor(s1, m, 64);
        s2 += __shfl_xor(s2, m, 64);
    }
    const float mu  = s1 * (1.f / DIM_);
    const float var = s2 * (1.f / DIM_) - mu * mu;
    const float rs  = rsqrtf(var + LN_EPS);

    float* __restrict__ o = out + (size_t)tg * DIM_ + h * DK_;
    #pragma unroll
    for (int k4 = 0; k4 < 8; k4++){
        float4 g4 = *reinterpret_cast<const float4*>(g + h * DK_ + k4 * 4);
        float4 b4 = *reinterpret_cast<const float4*>(b + h * DK_ + k4 * 4);
        float4 o4;
        o4.x = (acc[4*k4]   - mu) * rs * g4.x + b4.x;
        o4.y = (acc[4*k4+1] - mu) * rs * g4.y + b4.y;
        o4.z = (acc[4*k4+2] - mu) * rs * g4.z + b4.z;
        o4.w = (acc[4*k4+3] - mu) * rs * g4.w + b4.w;
        *reinterpret_cast<float4*>(o + k4 * 4) = o4;
    }
}

extern "C" void kernel_launch(void* const* d_in, const int* in_sizes, int n_in,
                              void* d_out, int out_size, void* d_ws, size_t ws_size,
                              hipStream_t stream)
{
    const float* x   = (const float*)d_in[0];
    const int*  ei   = (const int*)d_in[1];
    const int*  ntyp = (const int*)d_in[3];
    const int*  etyp = (const int*)d_in[4];
    const float* Wk  = (const float*)d_in[5];
    const float* bk  = (const float*)d_in[6];
    const float* Wq  = (const float*)d_in[7];
    const float* bq  = (const float*)d_in[8];
    const float* Wv  = (const float*)d_in[9];
    const float* bv  = (const float*)d_in[10];
    const float* pri = (const float*)d_in[11];
    const float* Wa  = (const float*)d_in[12];
    const float* Wm  = (const float*)d_in[13];
    const float* lg  = (const float*)d_in[14];
    const float* lb  = (const float*)d_in[15];

    const int n  = in_sizes[0] / DIM_;
    const int E_ = in_sizes[4];
    float* out = (float*)d_out;

    // ---- workspace layout ----
    float* fws = (float*)d_ws;
    const size_t NF = (size_t)n * DIM_;
    const size_t EH = (size_t)E_ * H_;
    float* Kb  = fws;
    float* Qb  = Kb + NF;
    float* Vb  = Qb + NF;
    float* SC  = Vb + NF;            // raw scores, edge order [E*H]
    float* SCC = SC + EH;            // exp scores, CSR order [E*H]
    int* iws     = (int*)(SCC + EH);
    int* sorted  = iws;              // n
    int* countsN = sorted + n;       // 8
    int* offsN   = countsN + 8;      // 8
    int* cursorN = offsN + 8;        // 8
    int* meta    = cursorN + 8;      // 1 + 3*maxtiles
    const int maxtiles = (n + 63) / 64 + NT_;
    int* ecnt    = meta + 1 + 3 * maxtiles;   // n
    int* eoff    = ecnt + n;                  // n + 1
    int* cursorE = eoff + n + 1;              // n
    int* bsum    = cursorE + n;               // <= 256
    int* payload = bsum + 256;                // E
    int* eidx    = payload + E_;              // E
    unsigned* gmax = (unsigned*)(eidx + E_);  // 24
    float*    gsum = (float*)(gmax + ET_ * H_);

    hipMemsetAsync(countsN, 0, 8 * sizeof(int), stream);
    hipMemsetAsync(ecnt, 0, (size_t)n * sizeof(int), stream);
    hipMemsetAsync(gmax, 0, ET_ * H_ * sizeof(unsigned), stream);
    hipMemsetAsync(gsum, 0, ET_ * H_ * sizeof(float), stream);

    // node type-sort + projections
    k_count  <<<(n + 255) / 256, 256, 0, stream>>>(ntyp, n, countsN);
    k_scan   <<<1, 1, 0, stream>>>(countsN, offsN, cursorN, meta);
    k_scatter<<<(n + 255) / 256, 256, 0, stream>>>(ntyp, n, cursorN, sorted);
    k_proj   <<<maxtiles, 256, 0, stream>>>(x, sorted, meta, Wk, bk, Wq, bq, Wv, bv, Kb, Qb, Vb);

    // edge CSR-by-target
    const int NB = (n + 255) / 256;
    k_ecount  <<<(E_ + 255) / 256, 256, 0, stream>>>(ei, E_, ecnt);
    k_scan1   <<<NB, 256, 0, stream>>>(ecnt, n, eoff, bsum);
    k_scan2   <<<1, 1, 0, stream>>>(bsum, NB);
    k_scan3   <<<NB, 256, 0, stream>>>(n, E_, bsum, eoff, cursorE);
    k_escatter<<<(E_ + 255) / 256, 256, 0, stream>>>(ei, etyp, E_, cursorE, payload, eidx);

    // scores -> softmax stats -> gather-aggregate + LN
    k_score<<<(int)((EH + 255) / 256), 256, 0, stream>>>(Kb, Qb, ei, etyp, Wa, pri, SC, gmax, E_);
    k_sum  <<<(int)((EH + 255) / 256), 256, 0, stream>>>(eidx, payload, gmax, SC, SCC, gsum, E_);
    k_aggln<<<(n * H_ + 255) / 256, 256, 0, stream>>>(Vb, x, eoff, payload, SCC, gsum, Wm, lg, lb, out, n);
}

// Round 3
// 1285.991 us; speedup vs baseline: 5.4616x; 1.7005x over previous
//
#include <hip/hip_runtime.h>
#include <math.h>

#define H_    8
#define DK_   32
#define NT_   6
#define ET_   3
#define DIM_  256
#define LN_EPS 1e-5f
#define NMATS (NT_ * 7)   // per node type: Q, Kt[0..2], Vt[0..2]

typedef __attribute__((ext_vector_type(8))) short short8v;
typedef __attribute__((ext_vector_type(4))) float f32x4;

__device__ __forceinline__ unsigned short f2bf(float f){
    unsigned u = __float_as_uint(f);
    return (unsigned short)((u + 0x7fffu + ((u >> 16) & 1u)) >> 16);
}
__device__ __forceinline__ float bflo(unsigned u){ return __uint_as_float(u << 16); }
__device__ __forceinline__ float bfhi(unsigned u){ return __uint_as_float(u & 0xFFFF0000u); }

// ---- float <-> sortable uint encoding for atomicMax on floats ----
__device__ __forceinline__ unsigned enc_f(float f){
    unsigned u = __float_as_uint(f);
    return (u & 0x80000000u) ? ~u : (u | 0x80000000u);
}
__device__ __forceinline__ float dec_f(unsigned u){
    return (u & 0x80000000u) ? __uint_as_float(u & 0x7fffffffu) : __uint_as_float(~u);
}

// ---------------- node type-sort ----------------
__global__ void k_count(const int* __restrict__ ntyp, int n, int* __restrict__ counts){
    int i = blockIdx.x * blockDim.x + threadIdx.x;
    if (i < n) atomicAdd(&counts[ntyp[i]], 1);
}

__global__ void k_scan(const int* __restrict__ counts, int* __restrict__ offs,
                       int* __restrict__ cursor, int* __restrict__ meta){
    int off = 0, ntl = 0;
    for (int t = 0; t < NT_; t++){
        offs[t] = off; cursor[t] = off;
        int c = counts[t];
        for (int s = 0; s < c; s += 64){
            meta[1 + 3*ntl]     = t;
            meta[1 + 3*ntl + 1] = off + s;
            meta[1 + 3*ntl + 2] = (c - s < 64) ? (c - s) : 64;
            ntl++;
        }
        off += c;
    }
    meta[0] = ntl;
}

__global__ void k_scatter(const int* __restrict__ ntyp, int n, int* __restrict__ cursor,
                          int* __restrict__ sorted){
    int i = blockIdx.x * blockDim.x + threadIdx.x;
    if (i < n){
        int t = ntyp[i];
        int pos = atomicAdd(&cursor[t], 1);
        sorted[pos] = i;
    }
}

// ---------------- weight fuse + MFMA-fragment pack ----------------
// pw layout: [matg][j(16)][p(8)][lane(64)][i(8)] bf16, matg = tn*7 + m
//   m=0: Wq ;  m=1..3: Wk @ blockdiag(Wa[te]) * (pri*inv_sqrt_dk) ;  m=4..6: Wv @ blockdiag(Wm[te])
// element(k, col) with col = j*16 + (lane&15), k = p*32 + (lane>>4)*8 + i
__global__ __launch_bounds__(256) void k_pack(
    const float* __restrict__ Wq, const float* __restrict__ Wk, const float* __restrict__ Wv,
    const float* __restrict__ Wa, const float* __restrict__ Wm, const float* __restrict__ pri,
    unsigned short* __restrict__ pw)
{
    const int gid = blockIdx.x * 256 + threadIdx.x;
    if (gid >= NMATS * 16 * 8 * 64) return;
    const int l = gid & 63;
    const int p = (gid >> 6) & 7;
    const int j = (gid >> 9) & 15;
    const int matg = gid >> 13;
    const int tn = matg / 7, m = matg % 7;
    const int col = j * 16 + (l & 15);
    const int k0  = p * 32 + (l >> 4) * 8;
    const int h = col >> 5, c = col & 31;

    float vals[8];
    if (m == 0){
        #pragma unroll
        for (int i = 0; i < 8; i++)
            vals[i] = Wq[((size_t)tn * 256 + (k0 + i)) * 256 + col];
    } else if (m <= 3){
        const int te = m - 1;
        const float scale = 0.17677669529663687f * pri[te * H_ + h];
        #pragma unroll
        for (int i = 0; i < 8; i++){
            const float* wk = Wk + ((size_t)tn * 256 + (k0 + i)) * 256 + h * 32;
            const float* wa = Wa + (size_t)te * 1024 + c;
            float s = 0.f;
            for (int d = 0; d < 32; d++) s = fmaf(wk[d], wa[d * 32], s);
            vals[i] = s * scale;
        }
    } else {
        const int te = m - 4;
        #pragma unroll
        for (int i = 0; i < 8; i++){
            const float* wv = Wv + ((size_t)tn * 256 + (k0 + i)) * 256 + h * 32;
            const float* wm = Wm + (size_t)te * 1024 + c;
            float s = 0.f;
            for (int d = 0; d < 32; d++) s = fmaf(wv[d], wm[d * 32], s);
            vals[i] = s;
        }
    }
    unsigned short o[8];
    #pragma unroll
    for (int i = 0; i < 8; i++) o[i] = f2bf(vals[i]);
    *reinterpret_cast<uint4*>(pw + (size_t)gid * 8) = *reinterpret_cast<const uint4*>(o);
}

__global__ void k_bias(
    const float* __restrict__ bq, const float* __restrict__ bk, const float* __restrict__ bv,
    const float* __restrict__ Wa, const float* __restrict__ Wm, const float* __restrict__ pri,
    float* __restrict__ bpack)
{
    const int gid = blockIdx.x * 256 + threadIdx.x;
    if (gid >= NMATS * 256) return;
    const int col = gid & 255;
    const int matg = gid >> 8;
    const int tn = matg / 7, m = matg % 7;
    const int h = col >> 5, c = col & 31;
    float v;
    if (m == 0) v = bq[tn * 256 + col];
    else if (m <= 3){
        const int te = m - 1;
        float s = 0.f;
        for (int d = 0; d < 32; d++) s = fmaf(bk[tn * 256 + h * 32 + d], Wa[te * 1024 + d * 32 + c], s);
        v = s * 0.17677669529663687f * pri[te * H_ + h];
    } else {
        const int te = m - 4;
        float s = 0.f;
        for (int d = 0; d < 32; d++) s = fmaf(bv[tn * 256 + h * 32 + d], Wm[te * 1024 + d * 32 + c], s);
        v = s;
    }
    bpack[gid] = v;
}

// ---------------- MFMA grouped projection ----------------
// block = 64-row type-uniform tile, 4 waves; computes 7 (64x256) GEMMs from one A-tile.
__global__ __launch_bounds__(256) void k_proj(
    const float* __restrict__ x, const int* __restrict__ sorted, const int* __restrict__ meta,
    const unsigned short* __restrict__ pw, const float* __restrict__ bpack,
    unsigned short* __restrict__ Qb, unsigned short* __restrict__ Ktb, unsigned short* __restrict__ Vtb)
{
    const int ntl = meta[0];
    if ((int)blockIdx.x >= ntl) return;
    const int tn    = meta[1 + 3*blockIdx.x];
    const int start = meta[1 + 3*blockIdx.x + 1];
    const int rows  = meta[1 + 3*blockIdx.x + 2];

    __shared__ unsigned short xs[64 * 256];   // 32 KB, XOR-swizzled bf16
    __shared__ int ids[64];
    const int tid = threadIdx.x;
    if (tid < 64) ids[tid] = sorted[start + ((tid < rows) ? tid : 0)];
    __syncthreads();

    // stage x tile: f32 -> bf16, swizzle byte ^= (row&7)<<4
    char* xb = reinterpret_cast<char*>(xs);
    for (int idx = tid; idx < 64 * 32; idx += 256){
        const int r = idx >> 5, c16 = idx & 31;
        const float* src = x + (size_t)ids[r] * DIM_ + c16 * 8;
        float4 a = *reinterpret_cast<const float4*>(src);
        float4 b = *reinterpret_cast<const float4*>(src + 4);
        unsigned short o[8] = {f2bf(a.x), f2bf(a.y), f2bf(a.z), f2bf(a.w),
                               f2bf(b.x), f2bf(b.y), f2bf(b.z), f2bf(b.w)};
        const int byte = r * 512 + ((c16 * 16) ^ ((r & 7) << 4));
        *reinterpret_cast<uint4*>(xb + byte) = *reinterpret_cast<const uint4*>(o);
    }
    __syncthreads();

    const int wid = tid >> 6, l = tid & 63;
    const int l15 = l & 15, lg = l >> 4;
    const int xorv = (l15 & 7) << 4;

    for (int m = 0; m < 7; m++){
        const int matg = tn * 7 + m;
        f32x4 acc[4][4];
        #pragma unroll
        for (int j = 0; j < 4; j++){
            const float bj = bpack[matg * 256 + wid * 64 + j * 16 + l15];
            #pragma unroll
            for (int i = 0; i < 4; i++) acc[i][j] = (f32x4){bj, bj, bj, bj};
        }

        for (int p = 0; p < 8; p++){
            short8v a[4], b[4];
            const int kb = (p * 64 + (lg << 4)) ^ xorv;
            #pragma unroll
            for (int i = 0; i < 4; i++)
                a[i] = *reinterpret_cast<const short8v*>(xb + (i * 16 + l15) * 512 + kb);
            #pragma unroll
            for (int j = 0; j < 4; j++){
                const int jg = wid * 4 + j;
                b[j] = *reinterpret_cast<const short8v*>(pw + ((((size_t)matg * 16 + jg) * 8 + p) * 64 + l) * 8);
            }
            #pragma unroll
            for (int i = 0; i < 4; i++)
                #pragma unroll
                for (int j = 0; j < 4; j++)
                    acc[i][j] = __builtin_amdgcn_mfma_f32_16x16x32_bf16(a[i], b[j], acc[i][j], 0, 0, 0);
        }

        // epilogue: C frag row=(lane>>4)*4+reg, col=lane&15 ; write bf16
        #pragma unroll
        for (int i = 0; i < 4; i++){
            #pragma unroll
            for (int r = 0; r < 4; r++){
                const int row = i * 16 + lg * 4 + r;
                if (row < rows){
                    const size_t node = (size_t)ids[row];
                    unsigned short* optr;
                    if (m == 0)       optr = Qb  + node * 256;
                    else if (m <= 3)  optr = Ktb + node * 768 + (size_t)(m - 1) * 256;
                    else              optr = Vtb + node * 768 + (size_t)(m - 4) * 256;
                    optr += wid * 64 + l15;
                    #pragma unroll
                    for (int j = 0; j < 4; j++) optr[j * 16] = f2bf(acc[i][j][r]);
                }
            }
        }
    }
}

// ---------------- edge CSR-by-target build ----------------
__global__ void k_ecount(const int* __restrict__ ei, int E_, int* __restrict__ ecnt){
    int e = blockIdx.x * blockDim.x + threadIdx.x;
    if (e < E_) atomicAdd(&ecnt[ei[E_ + e]], 1);
}

__global__ __launch_bounds__(256) void k_scan1(const int* __restrict__ ecnt, int n,
                                               int* __restrict__ excl, int* __restrict__ bsum){
    __shared__ int sh[256];
    const int tid = threadIdx.x;
    const int gi = blockIdx.x * 256 + tid;
    int v = (gi < n) ? ecnt[gi] : 0;
    sh[tid] = v;
    __syncthreads();
    for (int off = 1; off < 256; off <<= 1){
        int t = (tid >= off) ? sh[tid - off] : 0;
        __syncthreads();
        sh[tid] += t;
        __syncthreads();
    }
    if (gi < n) excl[gi] = sh[tid] - v;
    if (tid == 255) bsum[blockIdx.x] = sh[255];
}

__global__ void k_scan2(int* __restrict__ bsum, int nb){
    int run = 0;
    for (int b = 0; b < nb; b++){ int c = bsum[b]; bsum[b] = run; run += c; }
}

__global__ __launch_bounds__(256) void k_scan3(int n, int E_, const int* __restrict__ bsum,
                                               int* __restrict__ eoff, int* __restrict__ cursor){
    const int gi = blockIdx.x * 256 + threadIdx.x;
    if (gi < n){
        int v = eoff[gi] + bsum[blockIdx.x];
        eoff[gi] = v;
        cursor[gi] = v;
    }
    if (gi == 0) eoff[n] = E_;
}

__global__ void k_escatter(const int* __restrict__ ei, const int* __restrict__ etyp, int E_,
                           int* __restrict__ cursor, int* __restrict__ payload,
                           int* __restrict__ tgt){
    int e = blockIdx.x * blockDim.x + threadIdx.x;
    if (e < E_){
        int tg = ei[E_ + e];
        int pos = atomicAdd(&cursor[tg], 1);
        payload[pos] = ei[e] | (etyp[e] << 28);
        tgt[pos] = tg;
    }
}

// ---------------- scores (CSR order) + per-(type,head) max ----------------
__global__ __launch_bounds__(256) void k_score(
    const unsigned short* __restrict__ Ktb, const unsigned short* __restrict__ Qb,
    const int* __restrict__ payload, const int* __restrict__ tgt,
    float* __restrict__ SC, unsigned* __restrict__ gmax, int E_)
{
    __shared__ unsigned smax[ET_ * H_];
    const int tid = threadIdx.x;
    if (tid < ET_ * H_) smax[tid] = 0u;
    __syncthreads();
    const int idx = blockIdx.x * 256 + tid;
    if (idx < E_ * H_){
        const int pos = idx >> 3, h = idx & 7;
        const int pl = payload[pos];
        const int s = pl & 0x0FFFFFFF, t = pl >> 28;
        const int tg = tgt[pos];
        const unsigned short* kp = Ktb + ((size_t)s * 3 + t) * 256 + h * 32;
        const unsigned short* qp = Qb + (size_t)tg * 256 + h * 32;
        float acc = 0.f;
        #pragma unroll
        for (int k4 = 0; k4 < 4; k4++){
            uint4 kv = *reinterpret_cast<const uint4*>(kp + k4 * 8);
            uint4 qv = *reinterpret_cast<const uint4*>(qp + k4 * 8);
            acc = fmaf(bflo(kv.x), bflo(qv.x), acc); acc = fmaf(bfhi(kv.x), bfhi(qv.x), acc);
            acc = fmaf(bflo(kv.y), bflo(qv.y), acc); acc = fmaf(bfhi(kv.y), bfhi(qv.y), acc);
            acc = fmaf(bflo(kv.z), bflo(qv.z), acc); acc = fmaf(bfhi(kv.z), bfhi(qv.z), acc);
            acc = fmaf(bflo(kv.w), bflo(qv.w), acc); acc = fmaf(bfhi(kv.w), bfhi(qv.w), acc);
        }
        SC[idx] = acc;                       // scale+pri already folded into Kt weights
        atomicMax(&smax[t * H_ + h], enc_f(acc));
    }
    __syncthreads();
    if (tid < ET_ * H_) atomicMax(&gmax[tid], smax[tid]);
}

// ---------------- exp + per-(type,head) sum (in place, CSR order) ----------------
__global__ __launch_bounds__(256) void k_sum(
    const int* __restrict__ payload, const unsigned* __restrict__ gmax,
    float* __restrict__ SC, float* __restrict__ gsum, int E_)
{
    __shared__ float ssum[ET_ * H_];
    const int tid = threadIdx.x;
    if (tid < ET_ * H_) ssum[tid] = 0.f;
    __syncthreads();
    const int idx = blockIdx.x * 256 + tid;
    if (idx < E_ * H_){
        const int pos = idx >> 3, h = idx & 7;
        const int t = payload[pos] >> 28;
        const int bin = t * H_ + h;
        float v = __expf(SC[idx] - dec_f(gmax[bin]));
        SC[idx] = v;
        atomicAdd(&ssum[bin], v);
    }
    __syncthreads();
    if (tid < ET_ * H_ && ssum[tid] != 0.f) atomicAdd(&gsum[tid], ssum[tid]);
}

// ---------------- gather aggregation + skip + LayerNorm ----------------
__global__ __launch_bounds__(256) void k_aggln(
    const unsigned short* __restrict__ Vtb, const float* __restrict__ x,
    const int* __restrict__ eoff, const int* __restrict__ payload,
    const float* __restrict__ SC, const float* __restrict__ gsum,
    const float* __restrict__ g, const float* __restrict__ b,
    float* __restrict__ out, int n)
{
    const int idx = blockIdx.x * 256 + threadIdx.x;
    if (idx >= n * H_) return;
    const int tg = idx >> 3, h = idx & 7;

    float rw[ET_];
    #pragma unroll
    for (int t = 0; t < ET_; t++){
        float s = gsum[t * H_ + h];
        rw[t] = (s > 0.f) ? 1.f / s : 0.f;
    }

    float acc[DK_];
    #pragma unroll
    for (int k = 0; k < DK_; k++) acc[k] = 0.f;

    const int p1 = eoff[tg + 1];
    for (int pos = eoff[tg]; pos < p1; ++pos){
        const int pl = payload[pos];
        const int s = pl & 0x0FFFFFFF, t = pl >> 28;
        const float w = SC[pos * 8 + h] * rw[t];
        const unsigned short* vp = Vtb + ((size_t)s * 3 + t) * 256 + h * 32;
        #pragma unroll
        for (int k4 = 0; k4 < 4; k4++){
            uint4 vv = *reinterpret_cast<const uint4*>(vp + k4 * 8);
            acc[k4*8+0] = fmaf(w, bflo(vv.x), acc[k4*8+0]);
            acc[k4*8+1] = fmaf(w, bfhi(vv.x), acc[k4*8+1]);
            acc[k4*8+2] = fmaf(w, bflo(vv.y), acc[k4*8+2]);
            acc[k4*8+3] = fmaf(w, bfhi(vv.y), acc[k4*8+3]);
            acc[k4*8+4] = fmaf(w, bflo(vv.z), acc[k4*8+4]);
            acc[k4*8+5] = fmaf(w, bfhi(vv.z), acc[k4*8+5]);
            acc[k4*8+6] = fmaf(w, bflo(vv.w), acc[k4*8+6]);
            acc[k4*8+7] = fmaf(w, bfhi(vv.w), acc[k4*8+7]);
        }
    }

    // skip connection
    #pragma unroll
    for (int k4 = 0; k4 < 8; k4++){
        float4 x4 = *reinterpret_cast<const float4*>(x + (size_t)tg * DIM_ + h * DK_ + k4 * 4);
        acc[4*k4] += x4.x; acc[4*k4+1] += x4.y; acc[4*k4+2] += x4.z; acc[4*k4+3] += x4.w;
    }

    // LayerNorm across the 8 head-lanes of this target
    float s1 = 0.f, s2 = 0.f;
    #pragma unroll
    for (int k = 0; k < DK_; k++){ s1 += acc[k]; s2 = fmaf(acc[k], acc[k], s2); }
    #pragma unroll
    for (int m = 1; m <= 4; m <<= 1){
        s1 += __shfl_xor(s1, m, 64);
        s2 += __shfl_xor(s2, m, 64);
    }
    const float mu  = s1 * (1.f / DIM_);
    const float var = s2 * (1.f / DIM_) - mu * mu;
    const float rs  = rsqrtf(var + LN_EPS);

    float* __restrict__ o = out + (size_t)tg * DIM_ + h * DK_;
    #pragma unroll
    for (int k4 = 0; k4 < 8; k4++){
        float4 g4 = *reinterpret_cast<const float4*>(g + h * DK_ + k4 * 4);
        float4 b4 = *reinterpret_cast<const float4*>(b + h * DK_ + k4 * 4);
        float4 o4;
        o4.x = (acc[4*k4]   - mu) * rs * g4.x + b4.x;
        o4.y = (acc[4*k4+1] - mu) * rs * g4.y + b4.y;
        o4.z = (acc[4*k4+2] - mu) * rs * g4.z + b4.z;
        o4.w = (acc[4*k4+3] - mu) * rs * g4.w + b4.w;
        *reinterpret_cast<float4*>(o + k4 * 4) = o4;
    }
}

extern "C" void kernel_launch(void* const* d_in, const int* in_sizes, int n_in,
                              void* d_out, int out_size, void* d_ws, size_t ws_size,
                              hipStream_t stream)
{
    const float* x   = (const float*)d_in[0];
    const int*  ei   = (const int*)d_in[1];
    const int*  ntyp = (const int*)d_in[3];
    const int*  etyp = (const int*)d_in[4];
    const float* Wk  = (const float*)d_in[5];
    const float* bk  = (const float*)d_in[6];
    const float* Wq  = (const float*)d_in[7];
    const float* bq  = (const float*)d_in[8];
    const float* Wv  = (const float*)d_in[9];
    const float* bv  = (const float*)d_in[10];
    const float* pri = (const float*)d_in[11];
    const float* Wa  = (const float*)d_in[12];
    const float* Wm  = (const float*)d_in[13];
    const float* lg  = (const float*)d_in[14];
    const float* lb  = (const float*)d_in[15];

    const int n  = in_sizes[0] / DIM_;
    const int E_ = in_sizes[4];
    float* out = (float*)d_out;

    // ---- workspace layout ----
    const size_t NF = (size_t)n * DIM_;
    const size_t EH = (size_t)E_ * H_;
    unsigned short* Qb  = (unsigned short*)d_ws;          // n*256 bf16
    unsigned short* Ktb = Qb + NF;                        // n*3*256 bf16
    unsigned short* Vtb = Ktb + NF * 3;                   // n*3*256 bf16
    unsigned short* pwp = Vtb + NF * 3;                   // NMATS*65536 bf16
    float* SC    = (float*)(pwp + (size_t)NMATS * 65536); // E*8 f32 (CSR order)
    float* bpack = SC + EH;                               // NMATS*256
    int* sorted  = (int*)(bpack + NMATS * 256);           // n
    int* countsN = sorted + n;                            // 8
    int* offsN   = countsN + 8;                           // 8
    int* cursorN = offsN + 8;                             // 8
    int* meta    = cursorN + 8;                           // 1 + 3*maxtiles
    const int maxtiles = (n + 63) / 64 + NT_;
    int* ecnt    = meta + 1 + 3 * maxtiles;               // n
    int* eoff    = ecnt + n;                              // n + 1
    int* cursorE = eoff + n + 1;                          // n
    int* bsum    = cursorE + n;                           // <= 1024
    int* payload = bsum + 1024;                           // E
    int* tgt     = payload + E_;                          // E
    unsigned* gmax = (unsigned*)(tgt + E_);               // 24
    float*    gsum = (float*)(gmax + ET_ * H_);           // 24

    hipMemsetAsync(countsN, 0, 8 * sizeof(int), stream);
    hipMemsetAsync(ecnt, 0, (size_t)n * sizeof(int), stream);
    hipMemsetAsync(gmax, 0, ET_ * H_ * sizeof(unsigned), stream);
    hipMemsetAsync(gsum, 0, ET_ * H_ * sizeof(float), stream);

    // weight fuse/pack (independent of node data)
    k_pack<<<(NMATS * 16 * 8 * 64 + 255) / 256, 256, 0, stream>>>(Wq, Wk, Wv, Wa, Wm, pri, pwp);
    k_bias<<<(NMATS * 256 + 255) / 256, 256, 0, stream>>>(bq, bk, bv, Wa, Wm, pri, bpack);

    // node type-sort + fused MFMA projections
    k_count  <<<(n + 255) / 256, 256, 0, stream>>>(ntyp, n, countsN);
    k_scan   <<<1, 1, 0, stream>>>(countsN, offsN, cursorN, meta);
    k_scatter<<<(n + 255) / 256, 256, 0, stream>>>(ntyp, n, cursorN, sorted);
    k_proj   <<<maxtiles, 256, 0, stream>>>(x, sorted, meta, pwp, bpack, Qb, Ktb, Vtb);

    // edge CSR-by-target
    const int NB = (n + 255) / 256;
    k_ecount  <<<(E_ + 255) / 256, 256, 0, stream>>>(ei, E_, ecnt);
    k_scan1   <<<NB, 256, 0, stream>>>(ecnt, n, eoff, bsum);
    k_scan2   <<<1, 1, 0, stream>>>(bsum, NB);
    k_scan3   <<<NB, 256, 0, stream>>>(n, E_, bsum, eoff, cursorE);
    k_escatter<<<(E_ + 255) / 256, 256, 0, stream>>>(ei, etyp, E_, cursorE, payload, tgt);

    // scores -> softmax stats -> gather-aggregate + LN
    k_score<<<(int)((EH + 255) / 256), 256, 0, stream>>>(Ktb, Qb, payload, tgt, SC, gmax, E_);
    k_sum  <<<(int)((EH + 255) / 256), 256, 0, stream>>>(payload, gmax, SC, gsum, E_);
    k_aggln<<<(n * H_ + 255) / 256, 256, 0, stream>>>(Vtb, x, eoff, payload, SC, gsum, lg, lb, out, n);
}

// Round 4
// 869.565 us; speedup vs baseline: 8.0771x; 1.4789x over previous
//
#include <hip/hip_runtime.h>
#include <math.h>

#define H_    8
#define DK_   32
#define NT_   6
#define ET_   3
#define DIM_  256
#define LN_EPS 1e-5f
#define NMATS (NT_ * 7)   // per node type: Q, Kt[0..2], Vt[0..2]
#define NBLK  2048        // grid-stride blocks for edge passes
#define NBIN  (ET_ * H_)  // 24

typedef __attribute__((ext_vector_type(8))) short short8v;
typedef __attribute__((ext_vector_type(4))) float f32x4;

__device__ __forceinline__ unsigned short f2bf(float f){
    unsigned u = __float_as_uint(f);
    return (unsigned short)((u + 0x7fffu + ((u >> 16) & 1u)) >> 16);
}
__device__ __forceinline__ float bflo(unsigned u){ return __uint_as_float(u << 16); }
__device__ __forceinline__ float bfhi(unsigned u){ return __uint_as_float(u & 0xFFFF0000u); }

// ---------------- node type-sort ----------------
__global__ void k_count(const int* __restrict__ ntyp, int n, int* __restrict__ counts){
    int i = blockIdx.x * blockDim.x + threadIdx.x;
    if (i < n) atomicAdd(&counts[ntyp[i]], 1);
}

__global__ void k_scan(const int* __restrict__ counts, int* __restrict__ offs,
                       int* __restrict__ cursor, int* __restrict__ meta){
    int off = 0, ntl = 0;
    for (int t = 0; t < NT_; t++){
        offs[t] = off; cursor[t] = off;
        int c = counts[t];
        for (int s = 0; s < c; s += 64){
            meta[1 + 3*ntl]     = t;
            meta[1 + 3*ntl + 1] = off + s;
            meta[1 + 3*ntl + 2] = (c - s < 64) ? (c - s) : 64;
            ntl++;
        }
        off += c;
    }
    meta[0] = ntl;
}

__global__ void k_scatter(const int* __restrict__ ntyp, int n, int* __restrict__ cursor,
                          int* __restrict__ sorted){
    int i = blockIdx.x * blockDim.x + threadIdx.x;
    if (i < n){
        int t = ntyp[i];
        int pos = atomicAdd(&cursor[t], 1);
        sorted[pos] = i;
    }
}

// ---------------- weight fuse + MFMA-fragment pack ----------------
__global__ __launch_bounds__(256) void k_pack(
    const float* __restrict__ Wq, const float* __restrict__ Wk, const float* __restrict__ Wv,
    const float* __restrict__ Wa, const float* __restrict__ Wm, const float* __restrict__ pri,
    unsigned short* __restrict__ pw)
{
    const int gid = blockIdx.x * 256 + threadIdx.x;
    if (gid >= NMATS * 16 * 8 * 64) return;
    const int l = gid & 63;
    const int p = (gid >> 6) & 7;
    const int j = (gid >> 9) & 15;
    const int matg = gid >> 13;
    const int tn = matg / 7, m = matg % 7;
    const int col = j * 16 + (l & 15);
    const int k0  = p * 32 + (l >> 4) * 8;
    const int h = col >> 5, c = col & 31;

    float vals[8];
    if (m == 0){
        #pragma unroll
        for (int i = 0; i < 8; i++)
            vals[i] = Wq[((size_t)tn * 256 + (k0 + i)) * 256 + col];
    } else if (m <= 3){
        const int te = m - 1;
        const float scale = 0.17677669529663687f * pri[te * H_ + h];
        #pragma unroll
        for (int i = 0; i < 8; i++){
            const float* wk = Wk + ((size_t)tn * 256 + (k0 + i)) * 256 + h * 32;
            const float* wa = Wa + (size_t)te * 1024 + c;
            float s = 0.f;
            for (int d = 0; d < 32; d++) s = fmaf(wk[d], wa[d * 32], s);
            vals[i] = s * scale;
        }
    } else {
        const int te = m - 4;
        #pragma unroll
        for (int i = 0; i < 8; i++){
            const float* wv = Wv + ((size_t)tn * 256 + (k0 + i)) * 256 + h * 32;
            const float* wm = Wm + (size_t)te * 1024 + c;
            float s = 0.f;
            for (int d = 0; d < 32; d++) s = fmaf(wv[d], wm[d * 32], s);
            vals[i] = s;
        }
    }
    unsigned short o[8];
    #pragma unroll
    for (int i = 0; i < 8; i++) o[i] = f2bf(vals[i]);
    *reinterpret_cast<uint4*>(pw + (size_t)gid * 8) = *reinterpret_cast<const uint4*>(o);
}

__global__ void k_bias(
    const float* __restrict__ bq, const float* __restrict__ bk, const float* __restrict__ bv,
    const float* __restrict__ Wa, const float* __restrict__ Wm, const float* __restrict__ pri,
    float* __restrict__ bpack)
{
    const int gid = blockIdx.x * 256 + threadIdx.x;
    if (gid >= NMATS * 256) return;
    const int col = gid & 255;
    const int matg = gid >> 8;
    const int tn = matg / 7, m = matg % 7;
    const int h = col >> 5, c = col & 31;
    float v;
    if (m == 0) v = bq[tn * 256 + col];
    else if (m <= 3){
        const int te = m - 1;
        float s = 0.f;
        for (int d = 0; d < 32; d++) s = fmaf(bk[tn * 256 + h * 32 + d], Wa[te * 1024 + d * 32 + c], s);
        v = s * 0.17677669529663687f * pri[te * H_ + h];
    } else {
        const int te = m - 4;
        float s = 0.f;
        for (int d = 0; d < 32; d++) s = fmaf(bv[tn * 256 + h * 32 + d], Wm[te * 1024 + d * 32 + c], s);
        v = s;
    }
    bpack[gid] = v;
}

// ---------------- MFMA grouped projection ----------------
__global__ __launch_bounds__(256) void k_proj(
    const float* __restrict__ x, const int* __restrict__ sorted, const int* __restrict__ meta,
    const unsigned short* __restrict__ pw, const float* __restrict__ bpack,
    unsigned short* __restrict__ Qb, unsigned short* __restrict__ Ktb, unsigned short* __restrict__ Vtb)
{
    const int ntl = meta[0];
    if ((int)blockIdx.x >= ntl) return;
    const int tn    = meta[1 + 3*blockIdx.x];
    const int start = meta[1 + 3*blockIdx.x + 1];
    const int rows  = meta[1 + 3*blockIdx.x + 2];

    __shared__ unsigned short xs[64 * 256];   // 32 KB, XOR-swizzled bf16
    __shared__ int ids[64];
    const int tid = threadIdx.x;
    if (tid < 64) ids[tid] = sorted[start + ((tid < rows) ? tid : 0)];
    __syncthreads();

    char* xb = reinterpret_cast<char*>(xs);
    for (int idx = tid; idx < 64 * 32; idx += 256){
        const int r = idx >> 5, c16 = idx & 31;
        const float* src = x + (size_t)ids[r] * DIM_ + c16 * 8;
        float4 a = *reinterpret_cast<const float4*>(src);
        float4 b = *reinterpret_cast<const float4*>(src + 4);
        unsigned short o[8] = {f2bf(a.x), f2bf(a.y), f2bf(a.z), f2bf(a.w),
                               f2bf(b.x), f2bf(b.y), f2bf(b.z), f2bf(b.w)};
        const int byte = r * 512 + ((c16 * 16) ^ ((r & 7) << 4));
        *reinterpret_cast<uint4*>(xb + byte) = *reinterpret_cast<const uint4*>(o);
    }
    __syncthreads();

    const int wid = tid >> 6, l = tid & 63;
    const int l15 = l & 15, lg = l >> 4;
    const int xorv = (l15 & 7) << 4;

    for (int m = 0; m < 7; m++){
        const int matg = tn * 7 + m;
        f32x4 acc[4][4];
        #pragma unroll
        for (int j = 0; j < 4; j++){
            const float bj = bpack[matg * 256 + wid * 64 + j * 16 + l15];
            #pragma unroll
            for (int i = 0; i < 4; i++) acc[i][j] = (f32x4){bj, bj, bj, bj};
        }

        for (int p = 0; p < 8; p++){
            short8v a[4], b[4];
            const int kb = (p * 64 + (lg << 4)) ^ xorv;
            #pragma unroll
            for (int i = 0; i < 4; i++)
                a[i] = *reinterpret_cast<const short8v*>(xb + (i * 16 + l15) * 512 + kb);
            #pragma unroll
            for (int j = 0; j < 4; j++){
                const int jg = wid * 4 + j;
                b[j] = *reinterpret_cast<const short8v*>(pw + ((((size_t)matg * 16 + jg) * 8 + p) * 64 + l) * 8);
            }
            #pragma unroll
            for (int i = 0; i < 4; i++)
                #pragma unroll
                for (int j = 0; j < 4; j++)
                    acc[i][j] = __builtin_amdgcn_mfma_f32_16x16x32_bf16(a[i], b[j], acc[i][j], 0, 0, 0);
        }

        #pragma unroll
        for (int i = 0; i < 4; i++){
            #pragma unroll
            for (int r = 0; r < 4; r++){
                const int row = i * 16 + lg * 4 + r;
                if (row < rows){
                    const size_t node = (size_t)ids[row];
                    unsigned short* optr;
                    if (m == 0)       optr = Qb  + node * 256;
                    else if (m <= 3)  optr = Ktb + node * 768 + (size_t)(m - 1) * 256;
                    else              optr = Vtb + node * 768 + (size_t)(m - 4) * 256;
                    optr += wid * 64 + l15;
                    #pragma unroll
                    for (int j = 0; j < 4; j++) optr[j * 16] = f2bf(acc[i][j][r]);
                }
            }
        }
    }
}

// ---------------- edge CSR-by-target build ----------------
__global__ void k_ecount(const int* __restrict__ ei, int E_, int* __restrict__ ecnt){
    int e = blockIdx.x * blockDim.x + threadIdx.x;
    if (e < E_) atomicAdd(&ecnt[ei[E_ + e]], 1);
}

__global__ __launch_bounds__(256) void k_scan1(const int* __restrict__ ecnt, int n,
                                               int* __restrict__ excl, int* __restrict__ bsum){
    __shared__ int sh[256];
    const int tid = threadIdx.x;
    const int gi = blockIdx.x * 256 + tid;
    int v = (gi < n) ? ecnt[gi] : 0;
    sh[tid] = v;
    __syncthreads();
    for (int off = 1; off < 256; off <<= 1){
        int t = (tid >= off) ? sh[tid - off] : 0;
        __syncthreads();
        sh[tid] += t;
        __syncthreads();
    }
    if (gi < n) excl[gi] = sh[tid] - v;
    if (tid == 255) bsum[blockIdx.x] = sh[255];
}

__global__ void k_scan2(int* __restrict__ bsum, int nb){
    int run = 0;
    for (int b = 0; b < nb; b++){ int c = bsum[b]; bsum[b] = run; run += c; }
}

__global__ __launch_bounds__(256) void k_scan3(int n, int E_, const int* __restrict__ bsum,
                                               int* __restrict__ eoff, int* __restrict__ cursor){
    const int gi = blockIdx.x * 256 + threadIdx.x;
    if (gi < n){
        int v = eoff[gi] + bsum[blockIdx.x];
        eoff[gi] = v;
        cursor[gi] = v;
    }
    if (gi == 0) eoff[n] = E_;
}

__global__ void k_escatter(const int* __restrict__ ei, const int* __restrict__ etyp, int E_,
                           int* __restrict__ cursor, int* __restrict__ payload,
                           int* __restrict__ tgt){
    int e = blockIdx.x * blockDim.x + threadIdx.x;
    if (e < E_){
        int tg = ei[E_ + e];
        int pos = atomicAdd(&cursor[tg], 1);
        payload[pos] = ei[e] | (etyp[e] << 28);
        tgt[pos] = tg;
    }
}

// ---------------- scores (CSR order) + hierarchical per-(type,head) max ----------------
__global__ __launch_bounds__(256) void k_score(
    const unsigned short* __restrict__ Ktb, const unsigned short* __restrict__ Qb,
    const int* __restrict__ payload, const int* __restrict__ tgt,
    float* __restrict__ SC, float* __restrict__ pmax, int EH)
{
    const int tid = threadIdx.x;
    float m0 = -1e30f, m1 = -1e30f, m2 = -1e30f;

    for (int idx = blockIdx.x * 256 + tid; idx < EH; idx += NBLK * 256){
        const int pos = idx >> 3, h = idx & 7;
        const int pl = payload[pos];
        const int s = pl & 0x0FFFFFFF, t = pl >> 28;
        const int tg = tgt[pos];
        const unsigned short* kp = Ktb + ((size_t)s * 3 + t) * 256 + h * 32;
        const unsigned short* qp = Qb + (size_t)tg * 256 + h * 32;
        float acc = 0.f;
        #pragma unroll
        for (int k4 = 0; k4 < 4; k4++){
            uint4 kv = *reinterpret_cast<const uint4*>(kp + k4 * 8);
            uint4 qv = *reinterpret_cast<const uint4*>(qp + k4 * 8);
            acc = fmaf(bflo(kv.x), bflo(qv.x), acc); acc = fmaf(bfhi(kv.x), bfhi(qv.x), acc);
            acc = fmaf(bflo(kv.y), bflo(qv.y), acc); acc = fmaf(bfhi(kv.y), bfhi(qv.y), acc);
            acc = fmaf(bflo(kv.z), bflo(qv.z), acc); acc = fmaf(bfhi(kv.z), bfhi(qv.z), acc);
            acc = fmaf(bflo(kv.w), bflo(qv.w), acc); acc = fmaf(bfhi(kv.w), bfhi(qv.w), acc);
        }
        SC[idx] = acc;
        m0 = (t == 0) ? fmaxf(m0, acc) : m0;
        m1 = (t == 1) ? fmaxf(m1, acc) : m1;
        m2 = (t == 2) ? fmaxf(m2, acc) : m2;
    }

    // butterfly within wave over lanes sharing the same h (strides 8,16,32)
    #pragma unroll
    for (int s = 8; s <= 32; s <<= 1){
        m0 = fmaxf(m0, __shfl_xor(m0, s, 64));
        m1 = fmaxf(m1, __shfl_xor(m1, s, 64));
        m2 = fmaxf(m2, __shfl_xor(m2, s, 64));
    }
    __shared__ float sm[4][NBIN];
    const int wave = tid >> 6, lane = tid & 63;
    if (lane < 8){ sm[wave][lane] = m0; sm[wave][8 + lane] = m1; sm[wave][16 + lane] = m2; }
    __syncthreads();
    if (tid < NBIN)
        pmax[blockIdx.x * NBIN + tid] =
            fmaxf(fmaxf(sm[0][tid], sm[1][tid]), fmaxf(sm[2][tid], sm[3][tid]));
}

__global__ __launch_bounds__(256) void k_redmax(const float* __restrict__ pmax,
                                                float* __restrict__ gmax){
    const int b = blockIdx.x, tid = threadIdx.x;
    float m = -1e30f;
    for (int i = tid; i < NBLK; i += 256) m = fmaxf(m, pmax[i * NBIN + b]);
    #pragma unroll
    for (int s = 1; s < 64; s <<= 1) m = fmaxf(m, __shfl_xor(m, s, 64));
    __shared__ float sm[4];
    if ((tid & 63) == 0) sm[tid >> 6] = m;
    __syncthreads();
    if (tid == 0) gmax[b] = fmaxf(fmaxf(sm[0], sm[1]), fmaxf(sm[2], sm[3]));
}

// ---------------- exp-sum (read-only SC) -> per-block partials ----------------
__global__ __launch_bounds__(256) void k_expsum(
    const int* __restrict__ payload, const float* __restrict__ gmax,
    const float* __restrict__ SC, float* __restrict__ psum, int EH)
{
    const int tid = threadIdx.x;
    __shared__ float gm[NBIN];
    if (tid < NBIN) gm[tid] = gmax[tid];
    __syncthreads();

    float s0 = 0.f, s1 = 0.f, s2 = 0.f;
    for (int idx = blockIdx.x * 256 + tid; idx < EH; idx += NBLK * 256){
        const int pos = idx >> 3, h = idx & 7;
        const int t = payload[pos] >> 28;
        const float m = (t == 0) ? gm[h] : (t == 1) ? gm[8 + h] : gm[16 + h];
        const float v = __expf(SC[idx] - m);
        s0 += (t == 0) ? v : 0.f;
        s1 += (t == 1) ? v : 0.f;
        s2 += (t == 2) ? v : 0.f;
    }
    #pragma unroll
    for (int s = 8; s <= 32; s <<= 1){
        s0 += __shfl_xor(s0, s, 64);
        s1 += __shfl_xor(s1, s, 64);
        s2 += __shfl_xor(s2, s, 64);
    }
    __shared__ float sm[4][NBIN];
    const int wave = tid >> 6, lane = tid & 63;
    if (lane < 8){ sm[wave][lane] = s0; sm[wave][8 + lane] = s1; sm[wave][16 + lane] = s2; }
    __syncthreads();
    if (tid < NBIN)
        psum[blockIdx.x * NBIN + tid] = sm[0][tid] + sm[1][tid] + sm[2][tid] + sm[3][tid];
}

__global__ __launch_bounds__(256) void k_redsum(const float* __restrict__ psum,
                                                float* __restrict__ rw){
    const int b = blockIdx.x, tid = threadIdx.x;
    float s = 0.f;
    for (int i = tid; i < NBLK; i += 256) s += psum[i * NBIN + b];
    #pragma unroll
    for (int m = 1; m < 64; m <<= 1) s += __shfl_xor(s, m, 64);
    __shared__ float sm[4];
    if ((tid & 63) == 0) sm[tid >> 6] = s;
    __syncthreads();
    if (tid == 0){
        float t = sm[0] + sm[1] + sm[2] + sm[3];
        rw[b] = (t > 0.f) ? 1.f / t : 0.f;
    }
}

// ---------------- gather aggregation + skip + LayerNorm ----------------
__global__ __launch_bounds__(256) void k_aggln(
    const unsigned short* __restrict__ Vtb, const float* __restrict__ x,
    const int* __restrict__ eoff, const int* __restrict__ payload,
    const float* __restrict__ SC, const float* __restrict__ gmax, const float* __restrict__ rw,
    const float* __restrict__ g, const float* __restrict__ b,
    float* __restrict__ out, int n)
{
    const int idx = blockIdx.x * 256 + threadIdx.x;
    if (idx >= n * H_) return;
    const int tg = idx >> 3, h = idx & 7;

    const float mh0 = gmax[h],      mh1 = gmax[8 + h],  mh2 = gmax[16 + h];
    const float rw0 = rw[h],        rw1 = rw[8 + h],    rw2 = rw[16 + h];

    float acc[DK_];
    #pragma unroll
    for (int k = 0; k < DK_; k++) acc[k] = 0.f;

    const int p1 = eoff[tg + 1];
    for (int pos = eoff[tg]; pos < p1; ++pos){
        const int pl = payload[pos];
        const int s = pl & 0x0FFFFFFF, t = pl >> 28;
        const float m  = (t == 0) ? mh0 : (t == 1) ? mh1 : mh2;
        const float rwv= (t == 0) ? rw0 : (t == 1) ? rw1 : rw2;
        const float w = __expf(SC[pos * 8 + h] - m) * rwv;
        const unsigned short* vp = Vtb + ((size_t)s * 3 + t) * 256 + h * 32;
        #pragma unroll
        for (int k4 = 0; k4 < 4; k4++){
            uint4 vv = *reinterpret_cast<const uint4*>(vp + k4 * 8);
            acc[k4*8+0] = fmaf(w, bflo(vv.x), acc[k4*8+0]);
            acc[k4*8+1] = fmaf(w, bfhi(vv.x), acc[k4*8+1]);
            acc[k4*8+2] = fmaf(w, bflo(vv.y), acc[k4*8+2]);
            acc[k4*8+3] = fmaf(w, bfhi(vv.y), acc[k4*8+3]);
            acc[k4*8+4] = fmaf(w, bflo(vv.z), acc[k4*8+4]);
            acc[k4*8+5] = fmaf(w, bfhi(vv.z), acc[k4*8+5]);
            acc[k4*8+6] = fmaf(w, bflo(vv.w), acc[k4*8+6]);
            acc[k4*8+7] = fmaf(w, bfhi(vv.w), acc[k4*8+7]);
        }
    }

    #pragma unroll
    for (int k4 = 0; k4 < 8; k4++){
        float4 x4 = *reinterpret_cast<const float4*>(x + (size_t)tg * DIM_ + h * DK_ + k4 * 4);
        acc[4*k4] += x4.x; acc[4*k4+1] += x4.y; acc[4*k4+2] += x4.z; acc[4*k4+3] += x4.w;
    }

    float s1 = 0.f, s2 = 0.f;
    #pragma unroll
    for (int k = 0; k < DK_; k++){ s1 += acc[k]; s2 = fmaf(acc[k], acc[k], s2); }
    #pragma unroll
    for (int m = 1; m <= 4; m <<= 1){
        s1 += __shfl_xor(s1, m, 64);
        s2 += __shfl_xor(s2, m, 64);
    }
    const float mu  = s1 * (1.f / DIM_);
    const float var = s2 * (1.f / DIM_) - mu * mu;
    const float rs  = rsqrtf(var + LN_EPS);

    float* __restrict__ o = out + (size_t)tg * DIM_ + h * DK_;
    #pragma unroll
    for (int k4 = 0; k4 < 8; k4++){
        float4 g4 = *reinterpret_cast<const float4*>(g + h * DK_ + k4 * 4);
        float4 b4 = *reinterpret_cast<const float4*>(b + h * DK_ + k4 * 4);
        float4 o4;
        o4.x = (acc[4*k4]   - mu) * rs * g4.x + b4.x;
        o4.y = (acc[4*k4+1] - mu) * rs * g4.y + b4.y;
        o4.z = (acc[4*k4+2] - mu) * rs * g4.z + b4.z;
        o4.w = (acc[4*k4+3] - mu) * rs * g4.w + b4.w;
        *reinterpret_cast<float4*>(o + k4 * 4) = o4;
    }
}

extern "C" void kernel_launch(void* const* d_in, const int* in_sizes, int n_in,
                              void* d_out, int out_size, void* d_ws, size_t ws_size,
                              hipStream_t stream)
{
    const float* x   = (const float*)d_in[0];
    const int*  ei   = (const int*)d_in[1];
    const int*  ntyp = (const int*)d_in[3];
    const int*  etyp = (const int*)d_in[4];
    const float* Wk  = (const float*)d_in[5];
    const float* bk  = (const float*)d_in[6];
    const float* Wq  = (const float*)d_in[7];
    const float* bq  = (const float*)d_in[8];
    const float* Wv  = (const float*)d_in[9];
    const float* bv  = (const float*)d_in[10];
    const float* pri = (const float*)d_in[11];
    const float* Wa  = (const float*)d_in[12];
    const float* Wm  = (const float*)d_in[13];
    const float* lg  = (const float*)d_in[14];
    const float* lb  = (const float*)d_in[15];

    const int n  = in_sizes[0] / DIM_;
    const int E_ = in_sizes[4];
    const int EH = E_ * H_;
    float* out = (float*)d_out;

    // ---- workspace layout ----
    const size_t NF = (size_t)n * DIM_;
    unsigned short* Qb  = (unsigned short*)d_ws;          // n*256 bf16
    unsigned short* Ktb = Qb + NF;                        // n*3*256 bf16
    unsigned short* Vtb = Ktb + NF * 3;                   // n*3*256 bf16
    unsigned short* pwp = Vtb + NF * 3;                   // NMATS*65536 bf16
    float* SC    = (float*)(pwp + (size_t)NMATS * 65536); // E*8 f32 (CSR order)
    float* bpack = SC + (size_t)EH;                       // NMATS*256
    float* pmax  = bpack + NMATS * 256;                   // NBLK*24
    float* psum  = pmax + (size_t)NBLK * NBIN;            // NBLK*24
    float* gmax  = psum + (size_t)NBLK * NBIN;            // 24
    float* rw    = gmax + NBIN;                           // 24
    int* sorted  = (int*)(rw + NBIN);                     // n
    int* countsN = sorted + n;                            // 8
    int* offsN   = countsN + 8;                           // 8
    int* cursorN = offsN + 8;                             // 8
    int* meta    = cursorN + 8;                           // 1 + 3*maxtiles
    const int maxtiles = (n + 63) / 64 + NT_;
    int* ecnt    = meta + 1 + 3 * maxtiles;               // n
    int* eoff    = ecnt + n;                              // n + 1
    int* cursorE = eoff + n + 1;                          // n
    int* bsum    = cursorE + n;                           // <= 1024
    int* payload = bsum + 1024;                           // E
    int* tgt     = payload + E_;                          // E

    hipMemsetAsync(countsN, 0, 8 * sizeof(int), stream);
    hipMemsetAsync(ecnt, 0, (size_t)n * sizeof(int), stream);

    // weight fuse/pack
    k_pack<<<(NMATS * 16 * 8 * 64 + 255) / 256, 256, 0, stream>>>(Wq, Wk, Wv, Wa, Wm, pri, pwp);
    k_bias<<<(NMATS * 256 + 255) / 256, 256, 0, stream>>>(bq, bk, bv, Wa, Wm, pri, bpack);

    // node type-sort + fused MFMA projections
    k_count  <<<(n + 255) / 256, 256, 0, stream>>>(ntyp, n, countsN);
    k_scan   <<<1, 1, 0, stream>>>(countsN, offsN, cursorN, meta);
    k_scatter<<<(n + 255) / 256, 256, 0, stream>>>(ntyp, n, cursorN, sorted);
    k_proj   <<<maxtiles, 256, 0, stream>>>(x, sorted, meta, pwp, bpack, Qb, Ktb, Vtb);

    // edge CSR-by-target
    const int NB = (n + 255) / 256;
    k_ecount  <<<(E_ + 255) / 256, 256, 0, stream>>>(ei, E_, ecnt);
    k_scan1   <<<NB, 256, 0, stream>>>(ecnt, n, eoff, bsum);
    k_scan2   <<<1, 1, 0, stream>>>(bsum, NB);
    k_scan3   <<<NB, 256, 0, stream>>>(n, E_, bsum, eoff, cursorE);
    k_escatter<<<(E_ + 255) / 256, 256, 0, stream>>>(ei, etyp, E_, cursorE, payload, tgt);

    // scores -> hierarchical softmax stats -> gather-aggregate + LN
    k_score <<<NBLK, 256, 0, stream>>>(Ktb, Qb, payload, tgt, SC, pmax, EH);
    k_redmax<<<NBIN, 256, 0, stream>>>(pmax, gmax);
    k_expsum<<<NBLK, 256, 0, stream>>>(payload, gmax, SC, psum, EH);
    k_redsum<<<NBIN, 256, 0, stream>>>(psum, rw);
    k_aggln <<<(n * H_ + 255) / 256, 256, 0, stream>>>(Vtb, x, eoff, payload, SC, gmax, rw, lg, lb, out, n);
}

// Round 5
// 476.314 us; speedup vs baseline: 14.7456x; 1.8256x over previous
//
#include <hip/hip_runtime.h>
#include <math.h>

#define H_    8
#define DK_   32
#define NT_   6
#define ET_   3
#define DIM_  256
#define LN_EPS 1e-5f
#define NMATS (NT_ * 7)   // per node type: Q, Kt[0..2], Vt[0..2]
#define NBLK  2048        // grid-stride blocks for edge passes
#define NBIN  (ET_ * H_)  // 24

typedef __attribute__((ext_vector_type(8))) short short8v;
typedef __attribute__((ext_vector_type(4))) float f32x4;

__device__ __forceinline__ unsigned short f2bf(float f){
    unsigned u = __float_as_uint(f);
    return (unsigned short)((u + 0x7fffu + ((u >> 16) & 1u)) >> 16);
}
__device__ __forceinline__ float bflo(unsigned u){ return __uint_as_float(u << 16); }
__device__ __forceinline__ float bfhi(unsigned u){ return __uint_as_float(u & 0xFFFF0000u); }

// ---------------- node type-sort (atomic-free, deterministic) ----------------
// per-block type histogram via wave ballots
__global__ __launch_bounds__(256) void k_hist(const int* __restrict__ ntyp, int n,
                                              int* __restrict__ bhist){
    const int tid = threadIdx.x;
    const int gi = blockIdx.x * 256 + tid;
    const int wave = tid >> 6, lane = tid & 63;
    const int t = (gi < n) ? ntyp[gi] : -1;
    __shared__ int whist[4][8];
    #pragma unroll
    for (int tt = 0; tt < NT_; tt++){
        unsigned long long bal = __ballot(t == tt);
        if (lane == 0) whist[wave][tt] = __popcll(bal);
    }
    __syncthreads();
    if (tid < NT_)
        bhist[blockIdx.x * 8 + tid] =
            whist[0][tid] + whist[1][tid] + whist[2][tid] + whist[3][tid];
}

// single block: per-type exclusive scan over blocks, type offsets, tile meta
__global__ void k_scanhist(int* __restrict__ bhist, int nb,
                           int* __restrict__ offs, int* __restrict__ meta){
    const int t = threadIdx.x;
    __shared__ int tot[8];
    if (t < NT_){
        int run = 0;
        for (int b = 0; b < nb; b++){
            int c = bhist[b * 8 + t];
            bhist[b * 8 + t] = run;
            run += c;
        }
        tot[t] = run;
    }
    __syncthreads();
    if (t == 0){
        int off = 0, ntl = 0;
        for (int tt = 0; tt < NT_; tt++){
            offs[tt] = off;
            int c = tot[tt];
            for (int s = 0; s < c; s += 64){
                meta[1 + 3*ntl]     = tt;
                meta[1 + 3*ntl + 1] = off + s;
                meta[1 + 3*ntl + 2] = (c - s < 64) ? (c - s) : 64;
                ntl++;
            }
            off += c;
        }
        meta[0] = ntl;
    }
    __syncthreads();
    if (t < NT_){
        const int o = offs[t];
        for (int b = 0; b < nb; b++) bhist[b * 8 + t] += o;
    }
}

// deterministic rank scatter: global base + wave prefix + lane prefix
__global__ __launch_bounds__(256) void k_scatter2(const int* __restrict__ ntyp, int n,
                                                  const int* __restrict__ bhist,
                                                  int* __restrict__ sorted){
    const int tid = threadIdx.x;
    const int gi = blockIdx.x * 256 + tid;
    const int wave = tid >> 6, lane = tid & 63;
    const int t = (gi < n) ? ntyp[gi] : -1;
    __shared__ int whist[4][8];
    unsigned long long mybal = 0;
    #pragma unroll
    for (int tt = 0; tt < NT_; tt++){
        unsigned long long bal = __ballot(t == tt);
        if (lane == 0) whist[wave][tt] = __popcll(bal);
        if (t == tt) mybal = bal;
    }
    __syncthreads();
    if (gi < n){
        int wo = 0;
        for (int w = 0; w < wave; w++) wo += whist[w][t];
        const unsigned long long below = (lane == 0) ? 0ULL : (~0ULL >> (64 - lane));
        const int rank = bhist[blockIdx.x * 8 + t] + wo + __popcll(mybal & below);
        sorted[rank] = gi;
    }
}

// ---------------- weight fuse + MFMA-fragment pack ----------------
__global__ __launch_bounds__(256) void k_pack(
    const float* __restrict__ Wq, const float* __restrict__ Wk, const float* __restrict__ Wv,
    const float* __restrict__ Wa, const float* __restrict__ Wm, const float* __restrict__ pri,
    unsigned short* __restrict__ pw)
{
    const int gid = blockIdx.x * 256 + threadIdx.x;
    if (gid >= NMATS * 16 * 8 * 64) return;
    const int l = gid & 63;
    const int p = (gid >> 6) & 7;
    const int j = (gid >> 9) & 15;
    const int matg = gid >> 13;
    const int tn = matg / 7, m = matg % 7;
    const int col = j * 16 + (l & 15);
    const int k0  = p * 32 + (l >> 4) * 8;
    const int h = col >> 5, c = col & 31;

    float vals[8];
    if (m == 0){
        #pragma unroll
        for (int i = 0; i < 8; i++)
            vals[i] = Wq[((size_t)tn * 256 + (k0 + i)) * 256 + col];
    } else if (m <= 3){
        const int te = m - 1;
        const float scale = 0.17677669529663687f * pri[te * H_ + h];
        #pragma unroll
        for (int i = 0; i < 8; i++){
            const float* wk = Wk + ((size_t)tn * 256 + (k0 + i)) * 256 + h * 32;
            const float* wa = Wa + (size_t)te * 1024 + c;
            float s = 0.f;
            for (int d = 0; d < 32; d++) s = fmaf(wk[d], wa[d * 32], s);
            vals[i] = s * scale;
        }
    } else {
        const int te = m - 4;
        #pragma unroll
        for (int i = 0; i < 8; i++){
            const float* wv = Wv + ((size_t)tn * 256 + (k0 + i)) * 256 + h * 32;
            const float* wm = Wm + (size_t)te * 1024 + c;
            float s = 0.f;
            for (int d = 0; d < 32; d++) s = fmaf(wv[d], wm[d * 32], s);
            vals[i] = s;
        }
    }
    unsigned short o[8];
    #pragma unroll
    for (int i = 0; i < 8; i++) o[i] = f2bf(vals[i]);
    *reinterpret_cast<uint4*>(pw + (size_t)gid * 8) = *reinterpret_cast<const uint4*>(o);
}

__global__ void k_bias(
    const float* __restrict__ bq, const float* __restrict__ bk, const float* __restrict__ bv,
    const float* __restrict__ Wa, const float* __restrict__ Wm, const float* __restrict__ pri,
    float* __restrict__ bpack)
{
    const int gid = blockIdx.x * 256 + threadIdx.x;
    if (gid >= NMATS * 256) return;
    const int col = gid & 255;
    const int matg = gid >> 8;
    const int tn = matg / 7, m = matg % 7;
    const int h = col >> 5, c = col & 31;
    float v;
    if (m == 0) v = bq[tn * 256 + col];
    else if (m <= 3){
        const int te = m - 1;
        float s = 0.f;
        for (int d = 0; d < 32; d++) s = fmaf(bk[tn * 256 + h * 32 + d], Wa[te * 1024 + d * 32 + c], s);
        v = s * 0.17677669529663687f * pri[te * H_ + h];
    } else {
        const int te = m - 4;
        float s = 0.f;
        for (int d = 0; d < 32; d++) s = fmaf(bv[tn * 256 + h * 32 + d], Wm[te * 1024 + d * 32 + c], s);
        v = s;
    }
    bpack[gid] = v;
}

// ---------------- MFMA grouped projection ----------------
__global__ __launch_bounds__(256) void k_proj(
    const float* __restrict__ x, const int* __restrict__ sorted, const int* __restrict__ meta,
    const unsigned short* __restrict__ pw, const float* __restrict__ bpack,
    unsigned short* __restrict__ Qb, unsigned short* __restrict__ Ktb, unsigned short* __restrict__ Vtb)
{
    const int ntl = meta[0];
    if ((int)blockIdx.x >= ntl) return;
    const int tn    = meta[1 + 3*blockIdx.x];
    const int start = meta[1 + 3*blockIdx.x + 1];
    const int rows  = meta[1 + 3*blockIdx.x + 2];

    __shared__ unsigned short xs[64 * 256];   // 32 KB, XOR-swizzled bf16
    __shared__ int ids[64];
    const int tid = threadIdx.x;
    if (tid < 64) ids[tid] = sorted[start + ((tid < rows) ? tid : 0)];
    __syncthreads();

    char* xb = reinterpret_cast<char*>(xs);
    for (int idx = tid; idx < 64 * 32; idx += 256){
        const int r = idx >> 5, c16 = idx & 31;
        const float* src = x + (size_t)ids[r] * DIM_ + c16 * 8;
        float4 a = *reinterpret_cast<const float4*>(src);
        float4 b = *reinterpret_cast<const float4*>(src + 4);
        unsigned short o[8] = {f2bf(a.x), f2bf(a.y), f2bf(a.z), f2bf(a.w),
                               f2bf(b.x), f2bf(b.y), f2bf(b.z), f2bf(b.w)};
        const int byte = r * 512 + ((c16 * 16) ^ ((r & 7) << 4));
        *reinterpret_cast<uint4*>(xb + byte) = *reinterpret_cast<const uint4*>(o);
    }
    __syncthreads();

    const int wid = tid >> 6, l = tid & 63;
    const int l15 = l & 15, lg = l >> 4;
    const int xorv = (l15 & 7) << 4;

    for (int m = 0; m < 7; m++){
        const int matg = tn * 7 + m;
        f32x4 acc[4][4];
        #pragma unroll
        for (int j = 0; j < 4; j++){
            const float bj = bpack[matg * 256 + wid * 64 + j * 16 + l15];
            #pragma unroll
            for (int i = 0; i < 4; i++) acc[i][j] = (f32x4){bj, bj, bj, bj};
        }

        for (int p = 0; p < 8; p++){
            short8v a[4], b[4];
            const int kb = (p * 64 + (lg << 4)) ^ xorv;
            #pragma unroll
            for (int i = 0; i < 4; i++)
                a[i] = *reinterpret_cast<const short8v*>(xb + (i * 16 + l15) * 512 + kb);
            #pragma unroll
            for (int j = 0; j < 4; j++){
                const int jg = wid * 4 + j;
                b[j] = *reinterpret_cast<const short8v*>(pw + ((((size_t)matg * 16 + jg) * 8 + p) * 64 + l) * 8);
            }
            #pragma unroll
            for (int i = 0; i < 4; i++)
                #pragma unroll
                for (int j = 0; j < 4; j++)
                    acc[i][j] = __builtin_amdgcn_mfma_f32_16x16x32_bf16(a[i], b[j], acc[i][j], 0, 0, 0);
        }

        #pragma unroll
        for (int i = 0; i < 4; i++){
            #pragma unroll
            for (int r = 0; r < 4; r++){
                const int row = i * 16 + lg * 4 + r;
                if (row < rows){
                    const size_t node = (size_t)ids[row];
                    unsigned short* optr;
                    if (m == 0)       optr = Qb  + node * 256;
                    else if (m <= 3)  optr = Ktb + node * 768 + (size_t)(m - 1) * 256;
                    else              optr = Vtb + node * 768 + (size_t)(m - 4) * 256;
                    optr += wid * 64 + l15;
                    #pragma unroll
                    for (int j = 0; j < 4; j++) optr[j * 16] = f2bf(acc[i][j][r]);
                }
            }
        }
    }
}

// ---------------- edge CSR-by-target build ----------------
__global__ void k_ecount(const int* __restrict__ ei, int E_, int* __restrict__ ecnt){
    int e = blockIdx.x * blockDim.x + threadIdx.x;
    if (e < E_) atomicAdd(&ecnt[ei[E_ + e]], 1);
}

__global__ __launch_bounds__(256) void k_scan1(const int* __restrict__ ecnt, int n,
                                               int* __restrict__ excl, int* __restrict__ bsum){
    __shared__ int sh[256];
    const int tid = threadIdx.x;
    const int gi = blockIdx.x * 256 + tid;
    int v = (gi < n) ? ecnt[gi] : 0;
    sh[tid] = v;
    __syncthreads();
    for (int off = 1; off < 256; off <<= 1){
        int t = (tid >= off) ? sh[tid - off] : 0;
        __syncthreads();
        sh[tid] += t;
        __syncthreads();
    }
    if (gi < n) excl[gi] = sh[tid] - v;
    if (tid == 255) bsum[blockIdx.x] = sh[255];
}

__global__ void k_scan2(int* __restrict__ bsum, int nb){
    int run = 0;
    for (int b = 0; b < nb; b++){ int c = bsum[b]; bsum[b] = run; run += c; }
}

__global__ __launch_bounds__(256) void k_scan3(int n, int E_, const int* __restrict__ bsum,
                                               int* __restrict__ eoff, int* __restrict__ cursor){
    const int gi = blockIdx.x * 256 + threadIdx.x;
    if (gi < n){
        int v = eoff[gi] + bsum[blockIdx.x];
        eoff[gi] = v;
        cursor[gi] = v;
    }
    if (gi == 0) eoff[n] = E_;
}

__global__ void k_escatter(const int* __restrict__ ei, const int* __restrict__ etyp, int E_,
                           int* __restrict__ cursor, int* __restrict__ payload,
                           int* __restrict__ tgt){
    int e = blockIdx.x * blockDim.x + threadIdx.x;
    if (e < E_){
        int tg = ei[E_ + e];
        int pos = atomicAdd(&cursor[tg], 1);
        payload[pos] = ei[e] | (etyp[e] << 28);
        tgt[pos] = tg;
    }
}

// ---------------- scores (CSR order) + hierarchical per-(type,head) max ----------------
__global__ __launch_bounds__(256) void k_score(
    const unsigned short* __restrict__ Ktb, const unsigned short* __restrict__ Qb,
    const int* __restrict__ payload, const int* __restrict__ tgt,
    float* __restrict__ SC, float* __restrict__ pmax, int EH)
{
    const int tid = threadIdx.x;
    float m0 = -1e30f, m1 = -1e30f, m2 = -1e30f;

    for (int idx = blockIdx.x * 256 + tid; idx < EH; idx += NBLK * 256){
        const int pos = idx >> 3, h = idx & 7;
        const int pl = payload[pos];
        const int s = pl & 0x0FFFFFFF, t = pl >> 28;
        const int tg = tgt[pos];
        const unsigned short* kp = Ktb + ((size_t)s * 3 + t) * 256 + h * 32;
        const unsigned short* qp = Qb + (size_t)tg * 256 + h * 32;
        float acc = 0.f;
        #pragma unroll
        for (int k4 = 0; k4 < 4; k4++){
            uint4 kv = *reinterpret_cast<const uint4*>(kp + k4 * 8);
            uint4 qv = *reinterpret_cast<const uint4*>(qp + k4 * 8);
            acc = fmaf(bflo(kv.x), bflo(qv.x), acc); acc = fmaf(bfhi(kv.x), bfhi(qv.x), acc);
            acc = fmaf(bflo(kv.y), bflo(qv.y), acc); acc = fmaf(bfhi(kv.y), bfhi(qv.y), acc);
            acc = fmaf(bflo(kv.z), bflo(qv.z), acc); acc = fmaf(bfhi(kv.z), bfhi(qv.z), acc);
            acc = fmaf(bflo(kv.w), bflo(qv.w), acc); acc = fmaf(bfhi(kv.w), bfhi(qv.w), acc);
        }
        SC[idx] = acc;
        m0 = (t == 0) ? fmaxf(m0, acc) : m0;
        m1 = (t == 1) ? fmaxf(m1, acc) : m1;
        m2 = (t == 2) ? fmaxf(m2, acc) : m2;
    }

    #pragma unroll
    for (int s = 8; s <= 32; s <<= 1){
        m0 = fmaxf(m0, __shfl_xor(m0, s, 64));
        m1 = fmaxf(m1, __shfl_xor(m1, s, 64));
        m2 = fmaxf(m2, __shfl_xor(m2, s, 64));
    }
    __shared__ float sm[4][NBIN];
    const int wave = tid >> 6, lane = tid & 63;
    if (lane < 8){ sm[wave][lane] = m0; sm[wave][8 + lane] = m1; sm[wave][16 + lane] = m2; }
    __syncthreads();
    if (tid < NBIN)
        pmax[blockIdx.x * NBIN + tid] =
            fmaxf(fmaxf(sm[0][tid], sm[1][tid]), fmaxf(sm[2][tid], sm[3][tid]));
}

__global__ __launch_bounds__(256) void k_redmax(const float* __restrict__ pmax,
                                                float* __restrict__ gmax){
    const int b = blockIdx.x, tid = threadIdx.x;
    float m = -1e30f;
    for (int i = tid; i < NBLK; i += 256) m = fmaxf(m, pmax[i * NBIN + b]);
    #pragma unroll
    for (int s = 1; s < 64; s <<= 1) m = fmaxf(m, __shfl_xor(m, s, 64));
    __shared__ float sm[4];
    if ((tid & 63) == 0) sm[tid >> 6] = m;
    __syncthreads();
    if (tid == 0) gmax[b] = fmaxf(fmaxf(sm[0], sm[1]), fmaxf(sm[2], sm[3]));
}

// ---------------- exp-sum (read-only SC) -> per-block partials ----------------
__global__ __launch_bounds__(256) void k_expsum(
    const int* __restrict__ payload, const float* __restrict__ gmax,
    const float* __restrict__ SC, float* __restrict__ psum, int EH)
{
    const int tid = threadIdx.x;
    __shared__ float gm[NBIN];
    if (tid < NBIN) gm[tid] = gmax[tid];
    __syncthreads();

    float s0 = 0.f, s1 = 0.f, s2 = 0.f;
    for (int idx = blockIdx.x * 256 + tid; idx < EH; idx += NBLK * 256){
        const int pos = idx >> 3, h = idx & 7;
        const int t = payload[pos] >> 28;
        const float m = (t == 0) ? gm[h] : (t == 1) ? gm[8 + h] : gm[16 + h];
        const float v = __expf(SC[idx] - m);
        s0 += (t == 0) ? v : 0.f;
        s1 += (t == 1) ? v : 0.f;
        s2 += (t == 2) ? v : 0.f;
    }
    #pragma unroll
    for (int s = 8; s <= 32; s <<= 1){
        s0 += __shfl_xor(s0, s, 64);
        s1 += __shfl_xor(s1, s, 64);
        s2 += __shfl_xor(s2, s, 64);
    }
    __shared__ float sm[4][NBIN];
    const int wave = tid >> 6, lane = tid & 63;
    if (lane < 8){ sm[wave][lane] = s0; sm[wave][8 + lane] = s1; sm[wave][16 + lane] = s2; }
    __syncthreads();
    if (tid < NBIN)
        psum[blockIdx.x * NBIN + tid] = sm[0][tid] + sm[1][tid] + sm[2][tid] + sm[3][tid];
}

__global__ __launch_bounds__(256) void k_redsum(const float* __restrict__ psum,
                                                float* __restrict__ rw){
    const int b = blockIdx.x, tid = threadIdx.x;
    float s = 0.f;
    for (int i = tid; i < NBLK; i += 256) s += psum[i * NBIN + b];
    #pragma unroll
    for (int m = 1; m < 64; m <<= 1) s += __shfl_xor(s, m, 64);
    __shared__ float sm[4];
    if ((tid & 63) == 0) sm[tid >> 6] = s;
    __syncthreads();
    if (tid == 0){
        float t = sm[0] + sm[1] + sm[2] + sm[3];
        rw[b] = (t > 0.f) ? 1.f / t : 0.f;
    }
}

// ---------------- gather aggregation + skip + LayerNorm ----------------
__global__ __launch_bounds__(256) void k_aggln(
    const unsigned short* __restrict__ Vtb, const float* __restrict__ x,
    const int* __restrict__ eoff, const int* __restrict__ payload,
    const float* __restrict__ SC, const float* __restrict__ gmax, const float* __restrict__ rw,
    const float* __restrict__ g, const float* __restrict__ b,
    float* __restrict__ out, int n)
{
    const int idx = blockIdx.x * 256 + threadIdx.x;
    if (idx >= n * H_) return;
    const int tg = idx >> 3, h = idx & 7;

    const float mh0 = gmax[h],      mh1 = gmax[8 + h],  mh2 = gmax[16 + h];
    const float rw0 = rw[h],        rw1 = rw[8 + h],    rw2 = rw[16 + h];

    float acc[DK_];
    #pragma unroll
    for (int k = 0; k < DK_; k++) acc[k] = 0.f;

    const int p1 = eoff[tg + 1];
    for (int pos = eoff[tg]; pos < p1; ++pos){
        const int pl = payload[pos];
        const int s = pl & 0x0FFFFFFF, t = pl >> 28;
        const float m  = (t == 0) ? mh0 : (t == 1) ? mh1 : mh2;
        const float rwv= (t == 0) ? rw0 : (t == 1) ? rw1 : rw2;
        const float w = __expf(SC[pos * 8 + h] - m) * rwv;
        const unsigned short* vp = Vtb + ((size_t)s * 3 + t) * 256 + h * 32;
        #pragma unroll
        for (int k4 = 0; k4 < 4; k4++){
            uint4 vv = *reinterpret_cast<const uint4*>(vp + k4 * 8);
            acc[k4*8+0] = fmaf(w, bflo(vv.x), acc[k4*8+0]);
            acc[k4*8+1] = fmaf(w, bfhi(vv.x), acc[k4*8+1]);
            acc[k4*8+2] = fmaf(w, bflo(vv.y), acc[k4*8+2]);
            acc[k4*8+3] = fmaf(w, bfhi(vv.y), acc[k4*8+3]);
            acc[k4*8+4] = fmaf(w, bflo(vv.z), acc[k4*8+4]);
            acc[k4*8+5] = fmaf(w, bfhi(vv.z), acc[k4*8+5]);
            acc[k4*8+6] = fmaf(w, bflo(vv.w), acc[k4*8+6]);
            acc[k4*8+7] = fmaf(w, bfhi(vv.w), acc[k4*8+7]);
        }
    }

    #pragma unroll
    for (int k4 = 0; k4 < 8; k4++){
        float4 x4 = *reinterpret_cast<const float4*>(x + (size_t)tg * DIM_ + h * DK_ + k4 * 4);
        acc[4*k4] += x4.x; acc[4*k4+1] += x4.y; acc[4*k4+2] += x4.z; acc[4*k4+3] += x4.w;
    }

    float s1 = 0.f, s2 = 0.f;
    #pragma unroll
    for (int k = 0; k < DK_; k++){ s1 += acc[k]; s2 = fmaf(acc[k], acc[k], s2); }
    #pragma unroll
    for (int m = 1; m <= 4; m <<= 1){
        s1 += __shfl_xor(s1, m, 64);
        s2 += __shfl_xor(s2, m, 64);
    }
    const float mu  = s1 * (1.f / DIM_);
    const float var = s2 * (1.f / DIM_) - mu * mu;
    const float rs  = rsqrtf(var + LN_EPS);

    float* __restrict__ o = out + (size_t)tg * DIM_ + h * DK_;
    #pragma unroll
    for (int k4 = 0; k4 < 8; k4++){
        float4 g4 = *reinterpret_cast<const float4*>(g + h * DK_ + k4 * 4);
        float4 b4 = *reinterpret_cast<const float4*>(b + h * DK_ + k4 * 4);
        float4 o4;
        o4.x = (acc[4*k4]   - mu) * rs * g4.x + b4.x;
        o4.y = (acc[4*k4+1] - mu) * rs * g4.y + b4.y;
        o4.z = (acc[4*k4+2] - mu) * rs * g4.z + b4.z;
        o4.w = (acc[4*k4+3] - mu) * rs * g4.w + b4.w;
        *reinterpret_cast<float4*>(o + k4 * 4) = o4;
    }
}

extern "C" void kernel_launch(void* const* d_in, const int* in_sizes, int n_in,
                              void* d_out, int out_size, void* d_ws, size_t ws_size,
                              hipStream_t stream)
{
    const float* x   = (const float*)d_in[0];
    const int*  ei   = (const int*)d_in[1];
    const int*  ntyp = (const int*)d_in[3];
    const int*  etyp = (const int*)d_in[4];
    const float* Wk  = (const float*)d_in[5];
    const float* bk  = (const float*)d_in[6];
    const float* Wq  = (const float*)d_in[7];
    const float* bq  = (const float*)d_in[8];
    const float* Wv  = (const float*)d_in[9];
    const float* bv  = (const float*)d_in[10];
    const float* pri = (const float*)d_in[11];
    const float* Wa  = (const float*)d_in[12];
    const float* Wm  = (const float*)d_in[13];
    const float* lg  = (const float*)d_in[14];
    const float* lb  = (const float*)d_in[15];

    const int n  = in_sizes[0] / DIM_;
    const int E_ = in_sizes[4];
    const int EH = E_ * H_;
    float* out = (float*)d_out;

    // ---- workspace layout ----
    const size_t NF = (size_t)n * DIM_;
    unsigned short* Qb  = (unsigned short*)d_ws;          // n*256 bf16
    unsigned short* Ktb = Qb + NF;                        // n*3*256 bf16
    unsigned short* Vtb = Ktb + NF * 3;                   // n*3*256 bf16
    unsigned short* pwp = Vtb + NF * 3;                   // NMATS*65536 bf16
    float* SC    = (float*)(pwp + (size_t)NMATS * 65536); // E*8 f32 (CSR order)
    float* bpack = SC + (size_t)EH;                       // NMATS*256
    float* pmax  = bpack + NMATS * 256;                   // NBLK*24
    float* psum  = pmax + (size_t)NBLK * NBIN;            // NBLK*24
    float* gmax  = psum + (size_t)NBLK * NBIN;            // 24
    float* rw    = gmax + NBIN;                           // 24
    int* sorted  = (int*)(rw + NBIN);                     // n
    int* offsN   = sorted + n;                            // 8
    const int NB = (n + 255) / 256;
    int* bhist   = offsN + 8;                             // NB*8
    int* meta    = bhist + (size_t)NB * 8;                // 1 + 3*maxtiles
    const int maxtiles = (n + 63) / 64 + NT_;
    int* ecnt    = meta + 1 + 3 * maxtiles;               // n
    int* eoff    = ecnt + n;                              // n + 1
    int* cursorE = eoff + n + 1;                          // n
    int* bsum    = cursorE + n;                           // <= 1024
    int* payload = bsum + 1024;                           // E
    int* tgt     = payload + E_;                          // E

    hipMemsetAsync(ecnt, 0, (size_t)n * sizeof(int), stream);

    // weight fuse/pack
    k_pack<<<(NMATS * 16 * 8 * 64 + 255) / 256, 256, 0, stream>>>(Wq, Wk, Wv, Wa, Wm, pri, pwp);
    k_bias<<<(NMATS * 256 + 255) / 256, 256, 0, stream>>>(bq, bk, bv, Wa, Wm, pri, bpack);

    // node type-sort (deterministic, atomic-free) + fused MFMA projections
    k_hist    <<<NB, 256, 0, stream>>>(ntyp, n, bhist);
    k_scanhist<<<1, 64, 0, stream>>>(bhist, NB, offsN, meta);
    k_scatter2<<<NB, 256, 0, stream>>>(ntyp, n, bhist, sorted);
    k_proj    <<<maxtiles, 256, 0, stream>>>(x, sorted, meta, pwp, bpack, Qb, Ktb, Vtb);

    // edge CSR-by-target
    k_ecount  <<<(E_ + 255) / 256, 256, 0, stream>>>(ei, E_, ecnt);
    k_scan1   <<<NB, 256, 0, stream>>>(ecnt, n, eoff, bsum);
    k_scan2   <<<1, 1, 0, stream>>>(bsum, NB);
    k_scan3   <<<NB, 256, 0, stream>>>(n, E_, bsum, eoff, cursorE);
    k_escatter<<<(E_ + 255) / 256, 256, 0, stream>>>(ei, etyp, E_, cursorE, payload, tgt);

    // scores -> hierarchical softmax stats -> gather-aggregate + LN
    k_score <<<NBLK, 256, 0, stream>>>(Ktb, Qb, payload, tgt, SC, pmax, EH);
    k_redmax<<<NBIN, 256, 0, stream>>>(pmax, gmax);
    k_expsum<<<NBLK, 256, 0, stream>>>(payload, gmax, SC, psum, EH);
    k_redsum<<<NBIN, 256, 0, stream>>>(psum, rw);
    k_aggln <<<(n * H_ + 255) / 256, 256, 0, stream>>>(Vtb, x, eoff, payload, SC, gmax, rw, lg, lb, out, n);
}